// Round 19
// baseline (924.670 us; speedup 1.0000x reference)
//
#include <hip/hip_runtime.h>
#include <hip/hip_bf16.h>

#define NCRYST 256
#define AATOMS 64
#define KNBR   20
#define HID    128
#define LAT    256
#define NRBF   128
#define NBLK   3
#define NATOMS (NCRYST * AATOMS)   // 16384
#define NEDGE  (NATOMS * KNBR)     // 327680
#define NPART  4                   // agg partial slices per crystal
#define DQ     4096                // dist-table knots over [0, CUT]
#define PI_F   3.14159265358979323846f
#define CUT_F  6.0f
#define CHB    1040                // LDS A chunk stride: 1024 B payload + 16 B pad
#define EUPGRID 512
#define AGP    129                 // agg LDS pitch (f32): 129 % 32 == 1

typedef short short8 __attribute__((ext_vector_type(8)));   // 8 bf16 (4 VGPRs)
typedef float f32x4  __attribute__((ext_vector_type(4)));   // MFMA C/D

__device__ __forceinline__ float bf2f(__hip_bfloat16 x) { return __bfloat162float(x); }
__device__ __forceinline__ __hip_bfloat16 f2bf(float x) { return __float2bfloat16(x); }
__device__ __forceinline__ float s2f(short x) {
  return __uint_as_float(((unsigned)(unsigned short)x) << 16);
}
__device__ __forceinline__ short f2s(float x) {
  union { short s; __hip_bfloat16 b; } u; u.b = f2bf(x); return u.s;
}

#define DMA16(gptr, lptr) __builtin_amdgcn_global_load_lds( \
    (const __attribute__((address_space(1))) void*)(gptr),  \
    (__attribute__((address_space(3))) void*)(lptr), 16, 0, 0)

// ---------------------------------------------------------------- cart coords
__global__ void k_cart(const float* __restrict__ frac, const float* __restrict__ lengths,
                       const float* __restrict__ angles, float* __restrict__ cart) {
  int atom = blockIdx.x * blockDim.x + threadIdx.x;
  if (atom >= NATOMS) return;
  int c = atom >> 6;
  float al = angles[c*3+0] * (PI_F/180.f);
  float be = angles[c*3+1] * (PI_F/180.f);
  float ga = angles[c*3+2] * (PI_F/180.f);
  float ca = cosf(al), cb = cosf(be), cg = cosf(ga), sg = sinf(ga);
  float a = lengths[c*3+0], b = lengths[c*3+1], cl = lengths[c*3+2];
  float cx = cl * cb;
  float cy = cl * (ca - cb*cg) / sg;
  float cz = sqrtf(fmaxf(cl*cl - cx*cx - cy*cy, 1e-8f));
  float f0 = frac[atom*3+0], f1 = frac[atom*3+1], f2 = frac[atom*3+2];
  cart[atom*3+0] = f0*a + f1*(b*cg) + f2*cx;
  cart[atom*3+1] = f1*(b*sg) + f2*cy;
  cart[atom*3+2] = f2*cz;
}

// ---------------- edge geometry: unit + dist; also init fbuf[e] = b_force
__global__ void k_edge(const float* __restrict__ cart, const int* __restrict__ src,
                       const int* __restrict__ dst, float* __restrict__ unit,
                       float* __restrict__ dist, const float* __restrict__ b_force,
                       float* __restrict__ fbuf) {
  int e = blockIdx.x * blockDim.x + threadIdx.x;
  if (e >= NEDGE) return;
  int s = src[e], d = dst[e];
  float dx = cart[d*3+0] - cart[s*3+0];
  float dy = cart[d*3+1] - cart[s*3+1];
  float dz = cart[d*3+2] - cart[s*3+2];
  float dd = sqrtf(dx*dx + dy*dy + dz*dz + 1e-12f);
  float inv = 1.f / dd;
  dist[e] = dd;
  unit[e*3+0] = dx*inv; unit[e*3+1] = dy*inv; unit[e*3+2] = dz*inv;
  fbuf[e] = b_force[0];
}

// ---------------- dist tables: T[0]=rbf@W_edge[256:384], T[1+i]=rbf@Wb_rbf[i]
__global__ __launch_bounds__(128) void k_tab(const float* __restrict__ W_edge,
                                             const float* __restrict__ Wb_rbf,
                                             float* __restrict__ T) {
  int q = blockIdx.x, n = threadIdx.x;
  __shared__ float rv[128];
  float d = (float)q * (CUT_F / (float)(DQ - 1));
  float env = 0.5f * (cosf(PI_F * fminf(d * (1.f/CUT_F), 1.f)) + 1.f);
  float t = (d - (float)n * (CUT_F/(NRBF-1))) * ((NRBF-1)/CUT_F);
  rv[n] = expf(-t*t) * env;
  __syncthreads();
  float a0 = 0.f, a1 = 0.f, a2 = 0.f, a3 = 0.f;
  for (int j = 0; j < 128; ++j) {
    float r = rv[j];
    a0 = fmaf(r, W_edge[(256 + j)*128 + n], a0);
    a1 = fmaf(r, Wb_rbf[0*16384 + j*128 + n], a1);
    a2 = fmaf(r, Wb_rbf[1*16384 + j*128 + n], a2);
    a3 = fmaf(r, Wb_rbf[2*16384 + j*128 + n], a3);
  }
  T[(0*DQ + q)*128 + n] = a0;
  T[(1*DQ + q)*128 + n] = a1;
  T[(2*DQ + q)*128 + n] = a2;
  T[(3*DQ + q)*128 + n] = a3;
}

// ----------------- weights -> bf16 n-major K=128 blocks (W_in stays K=384)
__global__ void k_wcast(const float* __restrict__ W_in, const float* __restrict__ W_edge,
                        const float* __restrict__ Wb_upd, const float* __restrict__ Wb_msg,
                        const float* __restrict__ Wb_atom, const float* __restrict__ W_fc1,
                        const float* __restrict__ W_fc2, __hip_bfloat16* __restrict__ WT) {
  int idx = blockIdx.x * 256 + threadIdx.x;
  if (idx >= 360448) return;
  if (idx < 49152) {
    int n = idx / 384, k = idx % 384;
    WT[idx] = f2bf(W_in[k*128 + n]);
    return;
  }
  int t = idx - 49152;
  int b = t >> 14, q = t & 16383;
  int n = q >> 7, k = q & 127;
  const float* S; int krow;
  if (b == 0)       { S = W_edge; krow = k; }
  else if (b == 1)  { S = W_edge; krow = 128 + k; }
  else if (b <= 10) { int i = (b-2)/3, part = (b-2)%3;
                      S = Wb_upd + i*49152; krow = part*128 + k; }
  else if (b <= 13) { S = Wb_msg + (b-11)*16384; krow = k; }
  else if (b <= 16) { S = Wb_atom + (b-14)*16384; krow = k; }
  else if (b == 17) { S = W_fc1; krow = k; }
  else              { S = W_fc2; krow = k; }
  WT[idx] = f2bf(S[krow*128 + n]);
}

// ============ MFMA h: h = relu([emb[atype]|z]@W_in + b), 64 rows/block
__global__ __launch_bounds__(256) void k_hm(
    const int* __restrict__ atype, const float* __restrict__ z,
    const float* __restrict__ emb, const __hip_bfloat16* __restrict__ WTin,
    const float* __restrict__ b, float* __restrict__ h,
    __hip_bfloat16* __restrict__ h_bf) {
  const int tid = threadIdx.x;
  const int w = tid >> 6, lane = tid & 63, ln = lane & 15, qd = lane >> 4;
  const int row0w = blockIdx.x * 64 + w * 16;
  const int arow = row0w + ln;
  const float* esrc = emb + (size_t)atype[arow] * 128;
  const float* zsrc = z + (size_t)(arow >> 6) * LAT;

  short8 af[12];
#pragma unroll
  for (int ks = 0; ks < 4; ++ks) {
    float4 v0 = *(const float4*)(esrc + ks*32 + qd*8);
    float4 v1 = *(const float4*)(esrc + ks*32 + qd*8 + 4);
    af[ks] = (short8){f2s(v0.x),f2s(v0.y),f2s(v0.z),f2s(v0.w),
                      f2s(v1.x),f2s(v1.y),f2s(v1.z),f2s(v1.w)};
  }
#pragma unroll
  for (int ks = 4; ks < 12; ++ks) {
    float4 v0 = *(const float4*)(zsrc + (ks-4)*32 + qd*8);
    float4 v1 = *(const float4*)(zsrc + (ks-4)*32 + qd*8 + 4);
    af[ks] = (short8){f2s(v0.x),f2s(v0.y),f2s(v0.z),f2s(v0.w),
                      f2s(v1.x),f2s(v1.y),f2s(v1.z),f2s(v1.w)};
  }

  const short* Wb = (const short*)WTin + ln*384 + qd*8;
  f32x4 acc[8];
#pragma unroll
  for (int ct = 0; ct < 8; ++ct) acc[ct] = (f32x4){0,0,0,0};
#pragma unroll
  for (int ks = 0; ks < 12; ++ks)
#pragma unroll
    for (int ct = 0; ct < 8; ++ct)
      acc[ct] = __builtin_amdgcn_mfma_f32_16x16x32_bf16(af[ks],
                  *(const short8*)(Wb + ct*16*384 + ks*32), acc[ct], 0,0,0);

#pragma unroll
  for (int ct = 0; ct < 8; ++ct) {
    int col = ct*16 + ln;
    float bias = b[col];
#pragma unroll
    for (int reg = 0; reg < 4; ++reg) {
      int crow = row0w + qd*4 + reg;
      float v = fmaxf(acc[ct][reg] + bias, 0.f);
      size_t o = (size_t)crow*128 + col;
      h[o] = v;
      h_bf[o] = f2bf(v);
    }
  }
}

// ============ dual projection: O1 = A@WT1, O2 = A@WT2 (no bias/relu, bf16)
__global__ __launch_bounds__(256) void k_uv2(
    const __hip_bfloat16* __restrict__ A,
    const __hip_bfloat16* __restrict__ WT1, const __hip_bfloat16* __restrict__ WT2,
    __hip_bfloat16* __restrict__ O1, __hip_bfloat16* __restrict__ O2) {
  const int tid = threadIdx.x;
  const int w = tid >> 6, lane = tid & 63, ln = lane & 15, qd = lane >> 4;
  const int row0w = blockIdx.x * 64 + w * 16;
  const int arow = row0w + ln;

  short8 af[4];
  const short* pa = (const short*)A + (size_t)arow*128 + qd*8;
#pragma unroll
  for (int ks = 0; ks < 4; ++ks) af[ks] = *(const short8*)(pa + ks*32);

  f32x4 a1[8], a2[8];
#pragma unroll
  for (int ct = 0; ct < 8; ++ct) { a1[ct] = (f32x4){0,0,0,0}; a2[ct] = (f32x4){0,0,0,0}; }
#pragma unroll
  for (int ct = 0; ct < 8; ++ct) {
    const short* b1 = (const short*)WT1 + (ct*16 + ln)*128 + qd*8;
    const short* b2 = (const short*)WT2 + (ct*16 + ln)*128 + qd*8;
#pragma unroll
    for (int ks = 0; ks < 4; ++ks) {
      a1[ct] = __builtin_amdgcn_mfma_f32_16x16x32_bf16(af[ks], *(const short8*)(b1 + ks*32), a1[ct], 0,0,0);
      a2[ct] = __builtin_amdgcn_mfma_f32_16x16x32_bf16(af[ks], *(const short8*)(b2 + ks*32), a2[ct], 0,0,0);
    }
  }
#pragma unroll
  for (int ct = 0; ct < 8; ++ct) {
    int col = ct*16 + ln;
#pragma unroll
    for (int reg = 0; reg < 4; ++reg) {
      size_t o = (size_t)(row0w + qd*4 + reg)*128 + col;
      O1[o] = f2bf(a1[ct][reg]);
      O2[o] = f2bf(a2[ct][reg]);
    }
  }
}

// ============ m init v2: m = relu(u0[src] + v0[dst] + T0(d) + b)
__global__ __launch_bounds__(256) void k_minit(
    const int* __restrict__ src, const int* __restrict__ dst,
    const float* __restrict__ dist,
    const __hip_bfloat16* __restrict__ u0, const __hip_bfloat16* __restrict__ v0,
    const float* __restrict__ T0, const float* __restrict__ b,
    __hip_bfloat16* __restrict__ m) {
  const int t = threadIdx.x;
  const int li = t & 15, ei = t >> 4;
  float bcol[8];
#pragma unroll
  for (int u = 0; u < 8; ++u) bcol[u] = b[li*8 + u];

  int e[4]; float dd[4]; short8 us[4], vs[4];
#pragma unroll
  for (int g = 0; g < 4; ++g) {
    e[g] = blockIdx.x*64 + g*16 + ei;
    dd[g] = dist[e[g]];
    int s = src[e[g]], d = dst[e[g]];
    us[g] = *(const short8*)((const short*)u0 + (size_t)s*128 + li*8);
    vs[g] = *(const short8*)((const short*)v0 + (size_t)d*128 + li*8);
  }
  float t0v[4][8], t1v[4][8]; float fr[4]; bool in[4];
#pragma unroll
  for (int g = 0; g < 4; ++g) {
    in[g] = dd[g] < CUT_F;
    float x = fminf(dd[g], CUT_F) * ((float)(DQ - 1) / CUT_F);
    int i0 = (int)x;
    fr[g] = x - (float)i0;
    const float* tp = T0 + (size_t)i0*128 + li*8;
    *(float4*)&t0v[g][0] = *(const float4*)tp;
    *(float4*)&t0v[g][4] = *(const float4*)(tp + 4);
    *(float4*)&t1v[g][0] = *(const float4*)(tp + 128);
    *(float4*)&t1v[g][4] = *(const float4*)(tp + 132);
  }
#pragma unroll
  for (int g = 0; g < 4; ++g) {
    short8 o;
#pragma unroll
    for (int u = 0; u < 8; ++u) {
      float tv = in[g] ? fmaf(fr[g], t1v[g][u] - t0v[g][u], t0v[g][u]) : 0.f;
      float v = s2f(us[g][u]) + s2f(vs[g][u]) + tv + bcol[u];
      o[u] = f2s(fmaxf(v, 0.f));
    }
    *(uint4*)((short*)m + (size_t)e[g]*128 + li*8) = *(uint4*)&o;
  }
}

// ============ m update (K=128, B in LDS, persistent blocks, DMA dbuf)
template<int MODE>
__global__ __launch_bounds__(256) void k_eup(
    const int* __restrict__ src, const int* __restrict__ dst,
    __hip_bfloat16* __restrict__ m,
    const __hip_bfloat16* __restrict__ uu, const __hip_bfloat16* __restrict__ vv,
    const __hip_bfloat16* __restrict__ WTmm, const float* __restrict__ b,
    const float* __restrict__ Wf, float* __restrict__ fout) {
  __shared__ short Bs[128 * 132];                     // 33.8 KB
  __shared__ __align__(16) char Abuf[2][17 * CHB];    // 2 x 17.7 KB
  const int tid = threadIdx.x;
  const int w = tid >> 6, lane = tid & 63, ln = lane & 15, qd = lane >> 4;
  const int cg = w & 1, rh = w >> 1;
  const int NT = NEDGE / 64;

#pragma unroll
  for (int i = 0; i < 8; ++i) {
    int g = i * 256 + tid;
    int colb = g >> 4, ch = g & 15;
    *(uint4*)&Bs[colb*132 + ch*8] = ((const uint4*)((const short*)WTmm + colb*128))[ch];
  }

  float bias4[4], wf4[4];
#pragma unroll
  for (int ct = 0; ct < 4; ++ct) bias4[ct] = b[cg*64 + ct*16 + ln];
  if constexpr (MODE == 2) {
#pragma unroll
    for (int ct = 0; ct < 4; ++ct) wf4[ct] = Wf[cg*64 + ct*16 + ln];
  }

  {
    int tile = blockIdx.x;
#pragma unroll
    for (int t4 = 0; t4 < 4; ++t4) {
      int chunk = w * 4 + t4;
      const short* gp = (const short*)m + (size_t)(tile*64 + chunk*4)*128 + lane*8;
      DMA16(gp, Abuf[0] + chunk * CHB);
    }
  }

  int it = 0;
  for (int tile = blockIdx.x; tile < NT; tile += EUPGRID, ++it) {
    const int nb = it & 1;
    int ntile = tile + EUPGRID;
    if (ntile < NT) {
#pragma unroll
      for (int t4 = 0; t4 < 4; ++t4) {
        int chunk = w * 4 + t4;
        const short* gp = (const short*)m + (size_t)(ntile*64 + chunk*4)*128 + lane*8;
        DMA16(gp, Abuf[nb^1] + chunk * CHB);
      }
      __builtin_amdgcn_s_waitcnt(0x0F74);   // drain all but next tile's 4 DMAs
    } else {
      __builtin_amdgcn_s_waitcnt(0x0F70);   // drain everything
    }
    __syncthreads();

    const char* Ab = Abuf[nb];
    int e0 = tile * 64;

    f32x4 acc0[4], acc1[4];
#pragma unroll
    for (int ct = 0; ct < 4; ++ct) { acc0[ct] = (f32x4){0,0,0,0}; acc1[ct] = (f32x4){0,0,0,0}; }
    const int rowA = rh*32 + ln, rowB = rowA + 16;
#pragma unroll
    for (int ks = 0; ks < 4; ++ks) {
      short8 aA = *(const short8*)(Ab + (rowA>>2)*CHB + (rowA&3)*256 + ks*64 + qd*16);
      short8 aB = *(const short8*)(Ab + (rowB>>2)*CHB + (rowB&3)*256 + ks*64 + qd*16);
#pragma unroll
      for (int ct = 0; ct < 4; ++ct) {
        short8 bb = *(const short8*)&Bs[(cg*64 + ct*16 + ln)*132 + ks*32 + qd*8];
        acc0[ct] = __builtin_amdgcn_mfma_f32_16x16x32_bf16(aA, bb, acc0[ct], 0,0,0);
        acc1[ct] = __builtin_amdgcn_mfma_f32_16x16x32_bf16(aB, bb, acc1[ct], 0,0,0);
      }
    }

    float vreg[2][4][4];
#pragma unroll
    for (int mt = 0; mt < 2; ++mt) {
      const f32x4* acc = mt ? acc1 : acc0;
#pragma unroll
      for (int reg = 0; reg < 4; ++reg) {
        int lrow = rh*32 + mt*16 + qd*4 + reg;
        int e = e0 + lrow;
        int srow = src[e], drow = dst[e];
        float fp = 0.f;
#pragma unroll
        for (int ct = 0; ct < 4; ++ct) {
          int col = cg*64 + ct*16 + ln;
          float um = s2f(*((const short*)uu + (size_t)srow*128 + col));
          float vm = s2f(*((const short*)vv + (size_t)drow*128 + col));
          float res = s2f(*(const short*)(Ab + (lrow>>2)*CHB + (lrow&3)*256 + col*2));
          float val = fmaxf(acc[ct][reg] + bias4[ct] + um + vm, 0.f) + res;
          if constexpr (MODE == 1) vreg[mt][reg][ct] = val;
          else fp = fmaf(val, wf4[ct], fp);
        }
        if constexpr (MODE == 2) {
          fp += __shfl_xor(fp, 1, 64);
          fp += __shfl_xor(fp, 2, 64);
          fp += __shfl_xor(fp, 4, 64);
          fp += __shfl_xor(fp, 8, 64);
          if (ln == 0) atomicAdd(&fout[e], fp);
        }
      }
    }

    if constexpr (MODE == 1) {
      __syncthreads();
      short* res = (short*)Abuf[nb];
#pragma unroll
      for (int mt = 0; mt < 2; ++mt)
#pragma unroll
        for (int reg = 0; reg < 4; ++reg) {
          int lrow = rh*32 + mt*16 + qd*4 + reg;
#pragma unroll
          for (int ct = 0; ct < 4; ++ct)
            res[lrow*136 + cg*64 + ct*16 + ln] = f2s(vreg[mt][reg][ct]);
        }
      __syncthreads();
#pragma unroll
      for (int i = 0; i < 4; ++i) {
        int g = i * 256 + tid;
        int row = g >> 4, ch = g & 15;
        *(uint4*)((short*)m + (size_t)(e0 + row)*128 + ch*8) =
            *(const uint4*)((const char*)Abuf[nb] + row*272 + ch*16);
      }
      __syncthreads();
    } else {
      __syncthreads();
    }
  }
}

// ===== fused msg+segsum v5: 32-edge tiles, pipelined DMA, agg pitch 129.
// Per tile: phase A builds gate[32][132] cooperatively (each thread 2 edges);
// issue next tile's DMA (2 chunks/wave) + 2 dist prefetches; vmcnt(4); barrier;
// phase B: wave w computes col-tiles {2w,2w+1} over both 16-row halves.
__global__ __launch_bounds__(256) void k_msgagg(
    const __hip_bfloat16* __restrict__ m, const float* __restrict__ dist,
    const __hip_bfloat16* __restrict__ WmT, const float* __restrict__ bm,
    const float* __restrict__ Tg, const int* __restrict__ dst,
    __hip_bfloat16* __restrict__ aggP) {
  __shared__ float agg[64 * AGP];                    // 33.0 KB
  __shared__ float gate[32 * 132];                   // 16.9 KB
  __shared__ __align__(16) char Mb[2][8 * CHB];      // 16.6 KB (32 rows/tile)
  const int tid = threadIdx.x;
  const int c = blockIdx.x & 255, pq = blockIdx.x >> 8;
  const int w = tid >> 6, lane = tid & 63, ln = lane & 15, qd = lane >> 4;
  const int ei = tid >> 4, li = tid & 15;   // phase-A role (edges ei, ei+16)

  for (int i = tid; i < 64*AGP; i += 256) agg[i] = 0.f;
  float bias2[2];
#pragma unroll
  for (int ct = 0; ct < 2; ++ct) bias2[ct] = bm[(w*2+ct)*16 + ln];

  const int ebase = c * 1280 + pq * 320;

  // prologue: DMA m tile 0 (wave w stages chunks 2w, 2w+1); prefetch dist0
#pragma unroll
  for (int t2 = 0; t2 < 2; ++t2) {
    int chunk = w*2 + t2;
    const short* gp = (const short*)m + (size_t)(ebase + chunk*4)*128 + lane*8;
    DMA16(gp, Mb[0] + chunk * CHB);
  }
  float dn0 = dist[ebase + ei];
  float dn1 = dist[ebase + 16 + ei];
  __syncthreads();

  for (int s = 0; s < 10; ++s) {
    int e0 = ebase + s * 32;

    // ---- phase A: gate for 32 edges (2 per thread, coalesced table loads) --
#pragma unroll
    for (int hh = 0; hh < 2; ++hh) {
      float dd = hh ? dn1 : dn0;
      float msk = (dd < CUT_F) ? 1.f : 0.f;
      float x = fminf(dd, CUT_F) * ((float)(DQ - 1) / CUT_F);
      int i0 = (int)x;
      float fr = x - (float)i0;
      const float* tp = Tg + (size_t)i0*128 + li*8;
      float4 a0 = *(const float4*)tp;
      float4 a1 = *(const float4*)(tp + 4);
      float4 b0 = *(const float4*)(tp + 128);
      float4 b1 = *(const float4*)(tp + 132);
      float g8[8];
      g8[0] = msk * fmaf(fr, b0.x-a0.x, a0.x);
      g8[1] = msk * fmaf(fr, b0.y-a0.y, a0.y);
      g8[2] = msk * fmaf(fr, b0.z-a0.z, a0.z);
      g8[3] = msk * fmaf(fr, b0.w-a0.w, a0.w);
      g8[4] = msk * fmaf(fr, b1.x-a1.x, a1.x);
      g8[5] = msk * fmaf(fr, b1.y-a1.y, a1.y);
      g8[6] = msk * fmaf(fr, b1.z-a1.z, a1.z);
      g8[7] = msk * fmaf(fr, b1.w-a1.w, a1.w);
      *(float4*)&gate[(ei + 16*hh)*132 + li*8]     = *(float4*)&g8[0];
      *(float4*)&gate[(ei + 16*hh)*132 + li*8 + 4] = *(float4*)&g8[4];
    }

    // ---- issue next tile's DMA + dist prefetch ----
    if (s < 9) {
#pragma unroll
      for (int t2 = 0; t2 < 2; ++t2) {
        int chunk = w*2 + t2;
        const short* gp = (const short*)m + (size_t)(e0 + 32 + chunk*4)*128 + lane*8;
        DMA16(gp, Mb[(s+1) & 1] + chunk * CHB);
      }
      dn0 = dist[e0 + 32 + ei];
      dn1 = dist[e0 + 48 + ei];
      __builtin_amdgcn_s_waitcnt(0x0F74);   // keep {2 DMA, 2 dist} in flight
    } else {
      __builtin_amdgcn_s_waitcnt(0x0F70);   // drain everything
    }
    __syncthreads();   // gate + m(s) staged for all waves

    // ---- phase B: wave w computes col-tiles 2w, 2w+1, both 16-row halves ---
    const char* Ms = Mb[s & 1];
#pragma unroll
    for (int mh = 0; mh < 2; ++mh) {
      int r = mh*16 + ln;
      short8 am[4];
#pragma unroll
      for (int ks = 0; ks < 4; ++ks)
        am[ks] = *(const short8*)(Ms + (r>>2)*CHB + (r&3)*256 + ks*64 + qd*16);
      int d4[4];
#pragma unroll
      for (int reg = 0; reg < 4; ++reg)
        d4[reg] = dst[e0 + mh*16 + qd*4 + reg] & 63;

      f32x4 accM[2];
#pragma unroll
      for (int ct = 0; ct < 2; ++ct) accM[ct] = (f32x4){0,0,0,0};
#pragma unroll
      for (int ct = 0; ct < 2; ++ct) {
        const short* bmp = (const short*)WmT + ((w*2+ct)*16 + ln)*128 + qd*8;
#pragma unroll
        for (int ks = 0; ks < 4; ++ks)
          accM[ct] = __builtin_amdgcn_mfma_f32_16x16x32_bf16(am[ks],
                       *(const short8*)(bmp + ks*32), accM[ct], 0,0,0);
      }
#pragma unroll
      for (int ct = 0; ct < 2; ++ct) {
        int col = (w*2+ct)*16 + ln;
#pragma unroll
        for (int reg = 0; reg < 4; ++reg) {
          float g = gate[(mh*16 + qd*4 + reg)*132 + col];
          float v = fmaxf(accM[ct][reg] + bias2[ct], 0.f) * g;
          if (v != 0.f) atomicAdd(&agg[d4[reg]*AGP + col], v);
        }
      }
    }
    __syncthreads();   // protect gate + Mb[(s+1)&1] before next iteration
  }

  __hip_bfloat16* outp = aggP + ((size_t)pq * NATOMS + c * 64) * HID;
  for (int i = tid; i < 64*128; i += 256) {
    int a = i >> 7, col = i & 127;
    outp[a*HID + col] = f2bf(agg[a*AGP + col]);
  }
}

// ============ MFMA fc (K=128): Y = [res +] relu(A@W + b)
__global__ __launch_bounds__(256) void k_fcm(
    const __hip_bfloat16* __restrict__ A,       // nslice==1
    const __hip_bfloat16* __restrict__ slices,  // nslice==NPART
    int nslice,
    const __hip_bfloat16* __restrict__ WT, const float* __restrict__ b,
    const float* __restrict__ resIn,            // nullable
    float* __restrict__ Yf,                     // nullable
    __hip_bfloat16* __restrict__ Ybf) {         // nullable
  const int tid = threadIdx.x;
  const int w = tid >> 6, lane = tid & 63, ln = lane & 15, qd = lane >> 4;
  const int row0w = blockIdx.x * 64 + w * 16;
  const int arow = row0w + ln;

  short8 af[4];
  if (nslice == 1) {
    const short* pa = (const short*)A + (size_t)arow*128 + qd*8;
#pragma unroll
    for (int ks = 0; ks < 4; ++ks) af[ks] = *(const short8*)(pa + ks*32);
  } else {
#pragma unroll
    for (int ks = 0; ks < 4; ++ks) {
      float s[8] = {0,0,0,0,0,0,0,0};
#pragma unroll
      for (int p = 0; p < NPART; ++p) {
        short8 v = *(const short8*)((const short*)slices +
                     (size_t)p*NATOMS*128 + (size_t)arow*128 + qd*8 + ks*32);
#pragma unroll
        for (int u = 0; u < 8; ++u) s[u] += s2f(v[u]);
      }
      af[ks] = (short8){f2s(s[0]),f2s(s[1]),f2s(s[2]),f2s(s[3]),
                        f2s(s[4]),f2s(s[5]),f2s(s[6]),f2s(s[7])};
    }
  }

  const short* Wb = (const short*)WT + ln*128 + qd*8;
  f32x4 acc[8];
#pragma unroll
  for (int ct = 0; ct < 8; ++ct) acc[ct] = (f32x4){0,0,0,0};
#pragma unroll
  for (int ct = 0; ct < 8; ++ct)
#pragma unroll
    for (int ks = 0; ks < 4; ++ks)
      acc[ct] = __builtin_amdgcn_mfma_f32_16x16x32_bf16(af[ks],
                  *(const short8*)(Wb + ct*16*128 + ks*32), acc[ct], 0,0,0);

#pragma unroll
  for (int ct = 0; ct < 8; ++ct) {
    int col = ct*16 + ln;
    float bias = b[col];
#pragma unroll
    for (int reg = 0; reg < 4; ++reg) {
      int crow = row0w + qd*4 + reg;
      size_t o = (size_t)crow*128 + col;
      float v = fmaxf(acc[ct][reg] + bias, 0.f);
      if (resIn) v += resIn[o];
      if (Yf)  Yf[o] = v;
      if (Ybf) Ybf[o] = f2bf(v);
    }
  }
}

// ----------------------------------- pred_cart = segsum(f*unit) per crystal
__global__ void k_pcart(const float* __restrict__ f, const float* __restrict__ unit,
                        const int* __restrict__ dst, float* __restrict__ out) {
  __shared__ float acc[AATOMS * 3];
  int c = blockIdx.x, tid = threadIdx.x;  // 256 threads
  if (tid < AATOMS*3) acc[tid] = 0.f;
  __syncthreads();
  for (int t = tid; t < 1280; t += 256) {
    int e = c*1280 + t;
    int d = dst[e] & 63;
    float fv = f[e];
    atomicAdd(&acc[d*3+0], fv * unit[e*3+0]);
    atomicAdd(&acc[d*3+1], fv * unit[e*3+1]);
    atomicAdd(&acc[d*3+2], fv * unit[e*3+2]);
  }
  __syncthreads();
  if (tid < AATOMS*3) out[c*AATOMS*3 + tid] = acc[tid];
}

// ----------------------------------------- final fc3: (128 -> 2) per atom row
__global__ void k_fc3(const float* __restrict__ a2, const float* __restrict__ W,
                      const float* __restrict__ b, float* __restrict__ out) {
  int lane = threadIdx.x & 63;
  int wave = threadIdx.x >> 6;
  int row = blockIdx.x * 4 + wave;
  float x0 = a2[(size_t)row*HID + lane], x1 = a2[(size_t)row*HID + 64 + lane];
  float p0 = x0 * W[lane*2+0] + x1 * W[(64+lane)*2+0];
  float p1 = x0 * W[lane*2+1] + x1 * W[(64+lane)*2+1];
#pragma unroll
  for (int off = 32; off > 0; off >>= 1) {
    p0 += __shfl_down(p0, off, 64);
    p1 += __shfl_down(p1, off, 64);
  }
  if (lane == 0) {
    out[row*2+0] = p0 + b[0];
    out[row*2+1] = p1 + b[1];
  }
}

extern "C" void kernel_launch(void* const* d_in, const int* in_sizes, int n_in,
                              void* d_out, int out_size, void* d_ws, size_t ws_size,
                              hipStream_t stream) {
  const float* z        = (const float*)d_in[0];
  const float* frac     = (const float*)d_in[1];
  const float* lengths  = (const float*)d_in[2];
  const float* angles   = (const float*)d_in[3];
  const int*   atype    = (const int*)  d_in[4];
  const int*   src      = (const int*)  d_in[5];
  const int*   dst      = (const int*)  d_in[6];
  const float* emb      = (const float*)d_in[7];
  const float* W_in     = (const float*)d_in[8];
  const float* b_in     = (const float*)d_in[9];
  const float* W_edge   = (const float*)d_in[10];
  const float* b_edge   = (const float*)d_in[11];
  const float* Wb_rbf   = (const float*)d_in[12];
  const float* Wb_msg   = (const float*)d_in[13];
  const float* bb_msg   = (const float*)d_in[14];
  const float* Wb_atom  = (const float*)d_in[15];
  const float* bb_atom  = (const float*)d_in[16];
  const float* Wb_upd   = (const float*)d_in[17];
  const float* bb_upd   = (const float*)d_in[18];
  const float* W_force  = (const float*)d_in[19];
  const float* b_force  = (const float*)d_in[20];
  const float* W_fc1    = (const float*)d_in[21];
  const float* b_fc1    = (const float*)d_in[22];
  const float* W_fc2    = (const float*)d_in[23];
  const float* b_fc2    = (const float*)d_in[24];
  const float* W_fc3    = (const float*)d_in[25];
  const float* b_fc3    = (const float*)d_in[26];

  // ---- workspace layout (~175 MB) ----
  char* p = (char*)d_ws;
  float* cart = (float*)p;            p += (size_t)NATOMS*3*4;
  float* unit = (float*)p;            p += (size_t)NEDGE*3*4;
  float* dist = (float*)p;            p += (size_t)NEDGE*4;
  float* h    = (float*)p;            p += (size_t)NATOMS*HID*4;
  float* a2   = (float*)p;            p += (size_t)NATOMS*HID*4;
  float* fbuf = (float*)p;            p += (size_t)NEDGE*4;
  float* T    = (float*)p;            p += (size_t)4*DQ*128*4;
  __hip_bfloat16* h_bf = (__hip_bfloat16*)p; p += (size_t)NATOMS*HID*2;
  __hip_bfloat16* a1bf = (__hip_bfloat16*)p; p += (size_t)NATOMS*HID*2;
  __hip_bfloat16* u0t  = (__hip_bfloat16*)p; p += (size_t)NATOMS*HID*2;
  __hip_bfloat16* v0t  = (__hip_bfloat16*)p; p += (size_t)NATOMS*HID*2;
  __hip_bfloat16* uut  = (__hip_bfloat16*)p; p += (size_t)NATOMS*HID*2;
  __hip_bfloat16* vvt  = (__hip_bfloat16*)p; p += (size_t)NATOMS*HID*2;
  __hip_bfloat16* aggP = (__hip_bfloat16*)p; p += (size_t)NPART*NATOMS*HID*2;
  __hip_bfloat16* m    = (__hip_bfloat16*)p; p += (size_t)NEDGE*HID*2;
  __hip_bfloat16* WT   = (__hip_bfloat16*)p; p += (size_t)360448*2;

  __hip_bfloat16* WT_in   = WT;
  __hip_bfloat16* WTK     = WT + 49152;          // 19 K=128 blocks
  __hip_bfloat16* WT_u0   = WTK + 0*16384;
  __hip_bfloat16* WT_v0   = WTK + 1*16384;
  __hip_bfloat16* WT_updB = WTK + 2*16384;       // (uu,vv,mm) x 3
  __hip_bfloat16* WT_msg  = WTK + 11*16384;
  __hip_bfloat16* WT_atom = WTK + 14*16384;
  __hip_bfloat16* WT_fc1  = WTK + 17*16384;
  __hip_bfloat16* WT_fc2  = WTK + 18*16384;

  float* out_cart = (float*)d_out;
  float* out_at   = out_cart + NATOMS*3;

  k_wcast<<<1408, 256, 0, stream>>>(W_in, W_edge, Wb_upd, Wb_msg, Wb_atom,
                                    W_fc1, W_fc2, WT);
  k_tab<<<DQ, 128, 0, stream>>>(W_edge, Wb_rbf, T);
  k_cart<<<NATOMS/256, 256, 0, stream>>>(frac, lengths, angles, cart);
  k_edge<<<NEDGE/256, 256, 0, stream>>>(cart, src, dst, unit, dist, b_force, fbuf);
  k_hm<<<NATOMS/64, 256, 0, stream>>>(atype, z, emb, WT_in, b_in, h, h_bf);
  k_uv2<<<NATOMS/64, 256, 0, stream>>>(h_bf, WT_u0, WT_v0, u0t, v0t);
  k_minit<<<NEDGE/64, 256, 0, stream>>>(src, dst, dist, u0t, v0t, T, b_edge, m);

  for (int i = 0; i < NBLK; ++i) {
    k_msgagg<<<NCRYST*NPART, 256, 0, stream>>>(m, dist, WT_msg + i*16384,
                                               bb_msg + i*HID, T + (size_t)(1+i)*DQ*128,
                                               dst, aggP);
    k_fcm<<<NATOMS/64, 256, 0, stream>>>(nullptr, aggP, NPART, WT_atom + i*16384,
                                         bb_atom + i*HID, h, h, h_bf);
    k_uv2<<<NATOMS/64, 256, 0, stream>>>(h_bf, WT_updB + (3*i+0)*16384,
                                         WT_updB + (3*i+1)*16384, uut, vvt);
    if (i < NBLK-1) {
      k_eup<1><<<EUPGRID, 256, 0, stream>>>(src, dst, m, uut, vvt,
                                            WT_updB + (3*i+2)*16384, bb_upd + i*HID,
                                            nullptr, nullptr);
    } else {
      k_eup<2><<<EUPGRID, 256, 0, stream>>>(src, dst, m, uut, vvt,
                                            WT_updB + (3*i+2)*16384, bb_upd + i*HID,
                                            W_force, fbuf);
    }
  }
  k_pcart<<<NCRYST, 256, 0, stream>>>(fbuf, unit, dst, out_cart);
  k_fcm<<<NATOMS/64, 256, 0, stream>>>(h_bf, nullptr, 1, WT_fc1, b_fc1,
                                       nullptr, nullptr, a1bf);
  k_fcm<<<NATOMS/64, 256, 0, stream>>>(a1bf, nullptr, 1, WT_fc2, b_fc2,
                                       nullptr, a2, nullptr);
  k_fc3<<<NATOMS/4, 256, 0, stream>>>(a2, W_fc3, b_fc3, out_at);
}

// Round 20
// 876.922 us; speedup vs baseline: 1.0545x; 1.0545x over previous
//
#include <hip/hip_runtime.h>
#include <hip/hip_bf16.h>

#define NCRYST 256
#define AATOMS 64
#define KNBR   20
#define HID    128
#define LAT    256
#define NRBF   128
#define NBLK   3
#define NATOMS (NCRYST * AATOMS)   // 16384
#define NEDGE  (NATOMS * KNBR)     // 327680
#define NPART  8                   // agg partial slices per crystal
#define DQ     4096                // dist-table knots over [0, CUT]
#define PI_F   3.14159265358979323846f
#define CUT_F  6.0f
#define CHB    1040                // LDS A chunk stride: 1024 B payload + 16 B pad
#define EUPGRID 512

typedef short short8 __attribute__((ext_vector_type(8)));   // 8 bf16 (4 VGPRs)
typedef float f32x4  __attribute__((ext_vector_type(4)));   // MFMA C/D

__device__ __forceinline__ float bf2f(__hip_bfloat16 x) { return __bfloat162float(x); }
__device__ __forceinline__ __hip_bfloat16 f2bf(float x) { return __float2bfloat16(x); }
__device__ __forceinline__ float s2f(short x) {
  return __uint_as_float(((unsigned)(unsigned short)x) << 16);
}
__device__ __forceinline__ short f2s(float x) {
  union { short s; __hip_bfloat16 b; } u; u.b = f2bf(x); return u.s;
}

#define DMA16(gptr, lptr) __builtin_amdgcn_global_load_lds( \
    (const __attribute__((address_space(1))) void*)(gptr),  \
    (__attribute__((address_space(3))) void*)(lptr), 16, 0, 0)

// ---------------------------------------------------------------- cart coords
__global__ void k_cart(const float* __restrict__ frac, const float* __restrict__ lengths,
                       const float* __restrict__ angles, float* __restrict__ cart) {
  int atom = blockIdx.x * blockDim.x + threadIdx.x;
  if (atom >= NATOMS) return;
  int c = atom >> 6;
  float al = angles[c*3+0] * (PI_F/180.f);
  float be = angles[c*3+1] * (PI_F/180.f);
  float ga = angles[c*3+2] * (PI_F/180.f);
  float ca = cosf(al), cb = cosf(be), cg = cosf(ga), sg = sinf(ga);
  float a = lengths[c*3+0], b = lengths[c*3+1], cl = lengths[c*3+2];
  float cx = cl * cb;
  float cy = cl * (ca - cb*cg) / sg;
  float cz = sqrtf(fmaxf(cl*cl - cx*cx - cy*cy, 1e-8f));
  float f0 = frac[atom*3+0], f1 = frac[atom*3+1], f2 = frac[atom*3+2];
  cart[atom*3+0] = f0*a + f1*(b*cg) + f2*cx;
  cart[atom*3+1] = f1*(b*sg) + f2*cy;
  cart[atom*3+2] = f2*cz;
}

// ---------------- edge geometry: unit + dist; also init fbuf[e] = b_force
__global__ void k_edge(const float* __restrict__ cart, const int* __restrict__ src,
                       const int* __restrict__ dst, float* __restrict__ unit,
                       float* __restrict__ dist, const float* __restrict__ b_force,
                       float* __restrict__ fbuf) {
  int e = blockIdx.x * blockDim.x + threadIdx.x;
  if (e >= NEDGE) return;
  int s = src[e], d = dst[e];
  float dx = cart[d*3+0] - cart[s*3+0];
  float dy = cart[d*3+1] - cart[s*3+1];
  float dz = cart[d*3+2] - cart[s*3+2];
  float dd = sqrtf(dx*dx + dy*dy + dz*dz + 1e-12f);
  float inv = 1.f / dd;
  dist[e] = dd;
  unit[e*3+0] = dx*inv; unit[e*3+1] = dy*inv; unit[e*3+2] = dz*inv;
  fbuf[e] = b_force[0];
}

// ---------------- dist tables: T[0]=rbf@W_edge[256:384], T[1+i]=rbf@Wb_rbf[i]
__global__ __launch_bounds__(128) void k_tab(const float* __restrict__ W_edge,
                                             const float* __restrict__ Wb_rbf,
                                             float* __restrict__ T) {
  int q = blockIdx.x, n = threadIdx.x;
  __shared__ float rv[128];
  float d = (float)q * (CUT_F / (float)(DQ - 1));
  float env = 0.5f * (cosf(PI_F * fminf(d * (1.f/CUT_F), 1.f)) + 1.f);
  float t = (d - (float)n * (CUT_F/(NRBF-1))) * ((NRBF-1)/CUT_F);
  rv[n] = expf(-t*t) * env;
  __syncthreads();
  float a0 = 0.f, a1 = 0.f, a2 = 0.f, a3 = 0.f;
  for (int j = 0; j < 128; ++j) {
    float r = rv[j];
    a0 = fmaf(r, W_edge[(256 + j)*128 + n], a0);
    a1 = fmaf(r, Wb_rbf[0*16384 + j*128 + n], a1);
    a2 = fmaf(r, Wb_rbf[1*16384 + j*128 + n], a2);
    a3 = fmaf(r, Wb_rbf[2*16384 + j*128 + n], a3);
  }
  T[(0*DQ + q)*128 + n] = a0;
  T[(1*DQ + q)*128 + n] = a1;
  T[(2*DQ + q)*128 + n] = a2;
  T[(3*DQ + q)*128 + n] = a3;
}

// ----------------- weights -> bf16 n-major K=128 blocks (W_in stays K=384)
__global__ void k_wcast(const float* __restrict__ W_in, const float* __restrict__ W_edge,
                        const float* __restrict__ Wb_upd, const float* __restrict__ Wb_msg,
                        const float* __restrict__ Wb_atom, const float* __restrict__ W_fc1,
                        const float* __restrict__ W_fc2, __hip_bfloat16* __restrict__ WT) {
  int idx = blockIdx.x * 256 + threadIdx.x;
  if (idx >= 360448) return;
  if (idx < 49152) {
    int n = idx / 384, k = idx % 384;
    WT[idx] = f2bf(W_in[k*128 + n]);
    return;
  }
  int t = idx - 49152;
  int b = t >> 14, q = t & 16383;
  int n = q >> 7, k = q & 127;
  const float* S; int krow;
  if (b == 0)       { S = W_edge; krow = k; }
  else if (b == 1)  { S = W_edge; krow = 128 + k; }
  else if (b <= 10) { int i = (b-2)/3, part = (b-2)%3;
                      S = Wb_upd + i*49152; krow = part*128 + k; }
  else if (b <= 13) { S = Wb_msg + (b-11)*16384; krow = k; }
  else if (b <= 16) { S = Wb_atom + (b-14)*16384; krow = k; }
  else if (b == 17) { S = W_fc1; krow = k; }
  else              { S = W_fc2; krow = k; }
  WT[idx] = f2bf(S[krow*128 + n]);
}

// ============ MFMA h: h = relu([emb[atype]|z]@W_in + b), 64 rows/block
__global__ __launch_bounds__(256) void k_hm(
    const int* __restrict__ atype, const float* __restrict__ z,
    const float* __restrict__ emb, const __hip_bfloat16* __restrict__ WTin,
    const float* __restrict__ b, float* __restrict__ h,
    __hip_bfloat16* __restrict__ h_bf) {
  const int tid = threadIdx.x;
  const int w = tid >> 6, lane = tid & 63, ln = lane & 15, qd = lane >> 4;
  const int row0w = blockIdx.x * 64 + w * 16;
  const int arow = row0w + ln;
  const float* esrc = emb + (size_t)atype[arow] * 128;
  const float* zsrc = z + (size_t)(arow >> 6) * LAT;

  short8 af[12];
#pragma unroll
  for (int ks = 0; ks < 4; ++ks) {
    float4 v0 = *(const float4*)(esrc + ks*32 + qd*8);
    float4 v1 = *(const float4*)(esrc + ks*32 + qd*8 + 4);
    af[ks] = (short8){f2s(v0.x),f2s(v0.y),f2s(v0.z),f2s(v0.w),
                      f2s(v1.x),f2s(v1.y),f2s(v1.z),f2s(v1.w)};
  }
#pragma unroll
  for (int ks = 4; ks < 12; ++ks) {
    float4 v0 = *(const float4*)(zsrc + (ks-4)*32 + qd*8);
    float4 v1 = *(const float4*)(zsrc + (ks-4)*32 + qd*8 + 4);
    af[ks] = (short8){f2s(v0.x),f2s(v0.y),f2s(v0.z),f2s(v0.w),
                      f2s(v1.x),f2s(v1.y),f2s(v1.z),f2s(v1.w)};
  }

  const short* Wb = (const short*)WTin + ln*384 + qd*8;
  f32x4 acc[8];
#pragma unroll
  for (int ct = 0; ct < 8; ++ct) acc[ct] = (f32x4){0,0,0,0};
#pragma unroll
  for (int ks = 0; ks < 12; ++ks)
#pragma unroll
    for (int ct = 0; ct < 8; ++ct)
      acc[ct] = __builtin_amdgcn_mfma_f32_16x16x32_bf16(af[ks],
                  *(const short8*)(Wb + ct*16*384 + ks*32), acc[ct], 0,0,0);

#pragma unroll
  for (int ct = 0; ct < 8; ++ct) {
    int col = ct*16 + ln;
    float bias = b[col];
#pragma unroll
    for (int reg = 0; reg < 4; ++reg) {
      int crow = row0w + qd*4 + reg;
      float v = fmaxf(acc[ct][reg] + bias, 0.f);
      size_t o = (size_t)crow*128 + col;
      h[o] = v;
      h_bf[o] = f2bf(v);
    }
  }
}

// ============ dual projection: O1 = A@WT1, O2 = A@WT2 (no bias/relu, bf16)
__global__ __launch_bounds__(256) void k_uv2(
    const __hip_bfloat16* __restrict__ A,
    const __hip_bfloat16* __restrict__ WT1, const __hip_bfloat16* __restrict__ WT2,
    __hip_bfloat16* __restrict__ O1, __hip_bfloat16* __restrict__ O2) {
  const int tid = threadIdx.x;
  const int w = tid >> 6, lane = tid & 63, ln = lane & 15, qd = lane >> 4;
  const int row0w = blockIdx.x * 64 + w * 16;
  const int arow = row0w + ln;

  short8 af[4];
  const short* pa = (const short*)A + (size_t)arow*128 + qd*8;
#pragma unroll
  for (int ks = 0; ks < 4; ++ks) af[ks] = *(const short8*)(pa + ks*32);

  f32x4 a1[8], a2[8];
#pragma unroll
  for (int ct = 0; ct < 8; ++ct) { a1[ct] = (f32x4){0,0,0,0}; a2[ct] = (f32x4){0,0,0,0}; }
#pragma unroll
  for (int ct = 0; ct < 8; ++ct) {
    const short* b1 = (const short*)WT1 + (ct*16 + ln)*128 + qd*8;
    const short* b2 = (const short*)WT2 + (ct*16 + ln)*128 + qd*8;
#pragma unroll
    for (int ks = 0; ks < 4; ++ks) {
      a1[ct] = __builtin_amdgcn_mfma_f32_16x16x32_bf16(af[ks], *(const short8*)(b1 + ks*32), a1[ct], 0,0,0);
      a2[ct] = __builtin_amdgcn_mfma_f32_16x16x32_bf16(af[ks], *(const short8*)(b2 + ks*32), a2[ct], 0,0,0);
    }
  }
#pragma unroll
  for (int ct = 0; ct < 8; ++ct) {
    int col = ct*16 + ln;
#pragma unroll
    for (int reg = 0; reg < 4; ++reg) {
      size_t o = (size_t)(row0w + qd*4 + reg)*128 + col;
      O1[o] = f2bf(a1[ct][reg]);
      O2[o] = f2bf(a2[ct][reg]);
    }
  }
}

// ============ m init v2: m = relu(u0[src] + v0[dst] + T0(d) + b)
__global__ __launch_bounds__(256) void k_minit(
    const int* __restrict__ src, const int* __restrict__ dst,
    const float* __restrict__ dist,
    const __hip_bfloat16* __restrict__ u0, const __hip_bfloat16* __restrict__ v0,
    const float* __restrict__ T0, const float* __restrict__ b,
    __hip_bfloat16* __restrict__ m) {
  const int t = threadIdx.x;
  const int li = t & 15, ei = t >> 4;
  float bcol[8];
#pragma unroll
  for (int u = 0; u < 8; ++u) bcol[u] = b[li*8 + u];

  int e[4]; float dd[4]; short8 us[4], vs[4];
#pragma unroll
  for (int g = 0; g < 4; ++g) {
    e[g] = blockIdx.x*64 + g*16 + ei;
    dd[g] = dist[e[g]];
    int s = src[e[g]], d = dst[e[g]];
    us[g] = *(const short8*)((const short*)u0 + (size_t)s*128 + li*8);
    vs[g] = *(const short8*)((const short*)v0 + (size_t)d*128 + li*8);
  }
  float t0v[4][8], t1v[4][8]; float fr[4]; bool in[4];
#pragma unroll
  for (int g = 0; g < 4; ++g) {
    in[g] = dd[g] < CUT_F;
    float x = fminf(dd[g], CUT_F) * ((float)(DQ - 1) / CUT_F);
    int i0 = (int)x;
    fr[g] = x - (float)i0;
    const float* tp = T0 + (size_t)i0*128 + li*8;
    *(float4*)&t0v[g][0] = *(const float4*)tp;
    *(float4*)&t0v[g][4] = *(const float4*)(tp + 4);
    *(float4*)&t1v[g][0] = *(const float4*)(tp + 128);
    *(float4*)&t1v[g][4] = *(const float4*)(tp + 132);
  }
#pragma unroll
  for (int g = 0; g < 4; ++g) {
    short8 o;
#pragma unroll
    for (int u = 0; u < 8; ++u) {
      float tv = in[g] ? fmaf(fr[g], t1v[g][u] - t0v[g][u], t0v[g][u]) : 0.f;
      float v = s2f(us[g][u]) + s2f(vs[g][u]) + tv + bcol[u];
      o[u] = f2s(fmaxf(v, 0.f));
    }
    *(uint4*)((short*)m + (size_t)e[g]*128 + li*8) = *(uint4*)&o;
  }
}

// ============ m update (K=128, B in LDS, persistent blocks, DMA dbuf)
template<int MODE>
__global__ __launch_bounds__(256) void k_eup(
    const int* __restrict__ src, const int* __restrict__ dst,
    __hip_bfloat16* __restrict__ m,
    const __hip_bfloat16* __restrict__ uu, const __hip_bfloat16* __restrict__ vv,
    const __hip_bfloat16* __restrict__ WTmm, const float* __restrict__ b,
    const float* __restrict__ Wf, float* __restrict__ fout) {
  __shared__ short Bs[128 * 132];                     // 33.8 KB
  __shared__ __align__(16) char Abuf[2][17 * CHB];    // 2 x 17.7 KB
  const int tid = threadIdx.x;
  const int w = tid >> 6, lane = tid & 63, ln = lane & 15, qd = lane >> 4;
  const int cg = w & 1, rh = w >> 1;
  const int NT = NEDGE / 64;

#pragma unroll
  for (int i = 0; i < 8; ++i) {
    int g = i * 256 + tid;
    int colb = g >> 4, ch = g & 15;
    *(uint4*)&Bs[colb*132 + ch*8] = ((const uint4*)((const short*)WTmm + colb*128))[ch];
  }

  float bias4[4], wf4[4];
#pragma unroll
  for (int ct = 0; ct < 4; ++ct) bias4[ct] = b[cg*64 + ct*16 + ln];
  if constexpr (MODE == 2) {
#pragma unroll
    for (int ct = 0; ct < 4; ++ct) wf4[ct] = Wf[cg*64 + ct*16 + ln];
  }

  {
    int tile = blockIdx.x;
#pragma unroll
    for (int t4 = 0; t4 < 4; ++t4) {
      int chunk = w * 4 + t4;
      const short* gp = (const short*)m + (size_t)(tile*64 + chunk*4)*128 + lane*8;
      DMA16(gp, Abuf[0] + chunk * CHB);
    }
  }

  int it = 0;
  for (int tile = blockIdx.x; tile < NT; tile += EUPGRID, ++it) {
    const int nb = it & 1;
    int ntile = tile + EUPGRID;
    if (ntile < NT) {
#pragma unroll
      for (int t4 = 0; t4 < 4; ++t4) {
        int chunk = w * 4 + t4;
        const short* gp = (const short*)m + (size_t)(ntile*64 + chunk*4)*128 + lane*8;
        DMA16(gp, Abuf[nb^1] + chunk * CHB);
      }
      __builtin_amdgcn_s_waitcnt(0x0F74);   // drain all but next tile's 4 DMAs
    } else {
      __builtin_amdgcn_s_waitcnt(0x0F70);   // drain everything
    }
    __syncthreads();

    const char* Ab = Abuf[nb];
    int e0 = tile * 64;

    f32x4 acc0[4], acc1[4];
#pragma unroll
    for (int ct = 0; ct < 4; ++ct) { acc0[ct] = (f32x4){0,0,0,0}; acc1[ct] = (f32x4){0,0,0,0}; }
    const int rowA = rh*32 + ln, rowB = rowA + 16;
#pragma unroll
    for (int ks = 0; ks < 4; ++ks) {
      short8 aA = *(const short8*)(Ab + (rowA>>2)*CHB + (rowA&3)*256 + ks*64 + qd*16);
      short8 aB = *(const short8*)(Ab + (rowB>>2)*CHB + (rowB&3)*256 + ks*64 + qd*16);
#pragma unroll
      for (int ct = 0; ct < 4; ++ct) {
        short8 bb = *(const short8*)&Bs[(cg*64 + ct*16 + ln)*132 + ks*32 + qd*8];
        acc0[ct] = __builtin_amdgcn_mfma_f32_16x16x32_bf16(aA, bb, acc0[ct], 0,0,0);
        acc1[ct] = __builtin_amdgcn_mfma_f32_16x16x32_bf16(aB, bb, acc1[ct], 0,0,0);
      }
    }

    float vreg[2][4][4];
#pragma unroll
    for (int mt = 0; mt < 2; ++mt) {
      const f32x4* acc = mt ? acc1 : acc0;
#pragma unroll
      for (int reg = 0; reg < 4; ++reg) {
        int lrow = rh*32 + mt*16 + qd*4 + reg;
        int e = e0 + lrow;
        int srow = src[e], drow = dst[e];
        float fp = 0.f;
#pragma unroll
        for (int ct = 0; ct < 4; ++ct) {
          int col = cg*64 + ct*16 + ln;
          float um = s2f(*((const short*)uu + (size_t)srow*128 + col));
          float vm = s2f(*((const short*)vv + (size_t)drow*128 + col));
          float res = s2f(*(const short*)(Ab + (lrow>>2)*CHB + (lrow&3)*256 + col*2));
          float val = fmaxf(acc[ct][reg] + bias4[ct] + um + vm, 0.f) + res;
          if constexpr (MODE == 1) vreg[mt][reg][ct] = val;
          else fp = fmaf(val, wf4[ct], fp);
        }
        if constexpr (MODE == 2) {
          fp += __shfl_xor(fp, 1, 64);
          fp += __shfl_xor(fp, 2, 64);
          fp += __shfl_xor(fp, 4, 64);
          fp += __shfl_xor(fp, 8, 64);
          if (ln == 0) atomicAdd(&fout[e], fp);
        }
      }
    }

    if constexpr (MODE == 1) {
      __syncthreads();
      short* res = (short*)Abuf[nb];
#pragma unroll
      for (int mt = 0; mt < 2; ++mt)
#pragma unroll
        for (int reg = 0; reg < 4; ++reg) {
          int lrow = rh*32 + mt*16 + qd*4 + reg;
#pragma unroll
          for (int ct = 0; ct < 4; ++ct)
            res[lrow*136 + cg*64 + ct*16 + ln] = f2s(vreg[mt][reg][ct]);
        }
      __syncthreads();
#pragma unroll
      for (int i = 0; i < 4; ++i) {
        int g = i * 256 + tid;
        int row = g >> 4, ch = g & 15;
        *(uint4*)((short*)m + (size_t)(e0 + row)*128 + ch*8) =
            *(const uint4*)((const char*)Abuf[nb] + row*272 + ch*16);
      }
      __syncthreads();
    } else {
      __syncthreads();
    }
  }
}

// ===== fused msg+segsum v6: R18 pipeline + gate-table prefetch into regs.
// Per tile s: phase A computes gate from REGISTERS (loaded during tile s-1);
// then issue table loads(s+1) + m DMA(s+1) + dist(s+2); vmcnt(6); barrier;
// phase B: ds_read m frags, MFMA, gate from LDS, LDS atomics; barrier.
__global__ __launch_bounds__(256) void k_msgagg(
    const __hip_bfloat16* __restrict__ m, const float* __restrict__ dist,
    const __hip_bfloat16* __restrict__ WmT, const float* __restrict__ bm,
    const float* __restrict__ Tg, const int* __restrict__ dst,
    __hip_bfloat16* __restrict__ aggP) {
  __shared__ float agg[64 * 132];                    // 33.8 KB
  __shared__ float gate[16 * 132];                   //  8.4 KB
  __shared__ __align__(16) char Mb[2][4 * CHB];      //  8.3 KB (16 rows/tile)
  const int tid = threadIdx.x;
  const int c = blockIdx.x & 255, pq = blockIdx.x >> 8;
  const int w = tid >> 6, lane = tid & 63, ln = lane & 15, qd = lane >> 4;
  const int ei = tid >> 4, li = tid & 15;   // phase-A role

  for (int i = tid; i < 64*132; i += 256) agg[i] = 0.f;
  float bias2[2];
#pragma unroll
  for (int ct = 0; ct < 2; ++ct) bias2[ct] = bm[(w*2+ct)*16 + ln];

  const int ebase = c * 1280 + pq * 160;

  // prologue: DMA m tile 0; load dist0 (blocking) and table rows for tile 0
  {
    const short* gp = (const short*)m + (size_t)(ebase + w*4)*128 + lane*8;
    DMA16(gp, Mb[0] + w * CHB);
  }
  float4 ta0, ta1, tb0, tb1; float frc, mskc;
  {
    float d0 = dist[ebase + ei];
    mskc = (d0 < CUT_F) ? 1.f : 0.f;
    float x = fminf(d0, CUT_F) * ((float)(DQ - 1) / CUT_F);
    int i0 = (int)x;
    frc = x - (float)i0;
    const float* tp = Tg + (size_t)i0*128 + li*8;
    ta0 = *(const float4*)tp;
    ta1 = *(const float4*)(tp + 4);
    tb0 = *(const float4*)(tp + 128);
    tb1 = *(const float4*)(tp + 132);
  }
  float dnxt = dist[ebase + 16 + ei];
  __syncthreads();

  for (int s = 0; s < 10; ++s) {
    int e0 = ebase + s * 16;

    // ---- phase A: gate from prefetched table registers ----
    {
      float g8[8];
      g8[0] = mskc * fmaf(frc, tb0.x-ta0.x, ta0.x);
      g8[1] = mskc * fmaf(frc, tb0.y-ta0.y, ta0.y);
      g8[2] = mskc * fmaf(frc, tb0.z-ta0.z, ta0.z);
      g8[3] = mskc * fmaf(frc, tb0.w-ta0.w, ta0.w);
      g8[4] = mskc * fmaf(frc, tb1.x-ta1.x, ta1.x);
      g8[5] = mskc * fmaf(frc, tb1.y-ta1.y, ta1.y);
      g8[6] = mskc * fmaf(frc, tb1.z-ta1.z, ta1.z);
      g8[7] = mskc * fmaf(frc, tb1.w-ta1.w, ta1.w);
      *(float4*)&gate[ei*132 + li*8]     = *(float4*)&g8[0];
      *(float4*)&gate[ei*132 + li*8 + 4] = *(float4*)&g8[4];
    }

    // ---- issue: table(s+1) into regs, m DMA(s+1), dist(s+2) ----
    if (s < 9) {
      mskc = (dnxt < CUT_F) ? 1.f : 0.f;
      float x = fminf(dnxt, CUT_F) * ((float)(DQ - 1) / CUT_F);
      int i0 = (int)x;
      frc = x - (float)i0;
      const float* tp = Tg + (size_t)i0*128 + li*8;
      ta0 = *(const float4*)tp;
      ta1 = *(const float4*)(tp + 4);
      tb0 = *(const float4*)(tp + 128);
      tb1 = *(const float4*)(tp + 132);
      const short* gp = (const short*)m + (size_t)(e0 + 16 + w*4)*128 + lane*8;
      DMA16(gp, Mb[(s+1) & 1] + w * CHB);
      int dn_idx = (s < 8) ? (e0 + 32 + ei) : (e0 + 16 + ei);  // keep 1 load, in-bounds
      dnxt = dist[dn_idx];
      __builtin_amdgcn_s_waitcnt(0x0F76);   // keep {4 table, 1 DMA, 1 dist} in flight
    } else {
      __builtin_amdgcn_s_waitcnt(0x0F70);   // drain everything
    }
    __syncthreads();   // gate + m(s) staged for all waves

    // ---- phase B: wave w computes col-tiles 2w, 2w+1 ----
    const char* Ms = Mb[s & 1];
    short8 am[4];
#pragma unroll
    for (int ks = 0; ks < 4; ++ks)
      am[ks] = *(const short8*)(Ms + (ln>>2)*CHB + (ln&3)*256 + ks*64 + qd*16);
    int d4[4];
#pragma unroll
    for (int reg = 0; reg < 4; ++reg) d4[reg] = dst[e0 + qd*4 + reg] & 63;

    f32x4 accM[2];
#pragma unroll
    for (int ct = 0; ct < 2; ++ct) accM[ct] = (f32x4){0,0,0,0};
#pragma unroll
    for (int ct = 0; ct < 2; ++ct) {
      const short* bmp = (const short*)WmT + ((w*2+ct)*16 + ln)*128 + qd*8;
#pragma unroll
      for (int ks = 0; ks < 4; ++ks)
        accM[ct] = __builtin_amdgcn_mfma_f32_16x16x32_bf16(am[ks],
                     *(const short8*)(bmp + ks*32), accM[ct], 0,0,0);
    }
#pragma unroll
    for (int ct = 0; ct < 2; ++ct) {
      int col = (w*2+ct)*16 + ln;
#pragma unroll
      for (int reg = 0; reg < 4; ++reg) {
        float g = gate[(qd*4 + reg)*132 + col];
        float v = fmaxf(accM[ct][reg] + bias2[ct], 0.f) * g;
        if (v != 0.f) atomicAdd(&agg[d4[reg]*132 + col], v);
      }
    }
    __syncthreads();   // protect gate + Mb[(s+1)&1] before next iteration
  }

  __hip_bfloat16* outp = aggP + ((size_t)pq * NATOMS + c * 64) * HID;
  for (int i = tid; i < 64*128; i += 256) {
    int a = i >> 7, col = i & 127;
    outp[a*HID + col] = f2bf(agg[a*132 + col]);
  }
}

// ============ MFMA fc (K=128): Y = [res +] relu(A@W + b)
__global__ __launch_bounds__(256) void k_fcm(
    const __hip_bfloat16* __restrict__ A,       // nslice==1
    const __hip_bfloat16* __restrict__ slices,  // nslice==NPART
    int nslice,
    const __hip_bfloat16* __restrict__ WT, const float* __restrict__ b,
    const float* __restrict__ resIn,            // nullable
    float* __restrict__ Yf,                     // nullable
    __hip_bfloat16* __restrict__ Ybf) {         // nullable
  const int tid = threadIdx.x;
  const int w = tid >> 6, lane = tid & 63, ln = lane & 15, qd = lane >> 4;
  const int row0w = blockIdx.x * 64 + w * 16;
  const int arow = row0w + ln;

  short8 af[4];
  if (nslice == 1) {
    const short* pa = (const short*)A + (size_t)arow*128 + qd*8;
#pragma unroll
    for (int ks = 0; ks < 4; ++ks) af[ks] = *(const short8*)(pa + ks*32);
  } else {
#pragma unroll
    for (int ks = 0; ks < 4; ++ks) {
      float s[8] = {0,0,0,0,0,0,0,0};
#pragma unroll
      for (int p = 0; p < NPART; ++p) {
        short8 v = *(const short8*)((const short*)slices +
                     (size_t)p*NATOMS*128 + (size_t)arow*128 + qd*8 + ks*32);
#pragma unroll
        for (int u = 0; u < 8; ++u) s[u] += s2f(v[u]);
      }
      af[ks] = (short8){f2s(s[0]),f2s(s[1]),f2s(s[2]),f2s(s[3]),
                        f2s(s[4]),f2s(s[5]),f2s(s[6]),f2s(s[7])};
    }
  }

  const short* Wb = (const short*)WT + ln*128 + qd*8;
  f32x4 acc[8];
#pragma unroll
  for (int ct = 0; ct < 8; ++ct) acc[ct] = (f32x4){0,0,0,0};
#pragma unroll
  for (int ct = 0; ct < 8; ++ct)
#pragma unroll
    for (int ks = 0; ks < 4; ++ks)
      acc[ct] = __builtin_amdgcn_mfma_f32_16x16x32_bf16(af[ks],
                  *(const short8*)(Wb + ct*16*128 + ks*32), acc[ct], 0,0,0);

#pragma unroll
  for (int ct = 0; ct < 8; ++ct) {
    int col = ct*16 + ln;
    float bias = b[col];
#pragma unroll
    for (int reg = 0; reg < 4; ++reg) {
      int crow = row0w + qd*4 + reg;
      size_t o = (size_t)crow*128 + col;
      float v = fmaxf(acc[ct][reg] + bias, 0.f);
      if (resIn) v += resIn[o];
      if (Yf)  Yf[o] = v;
      if (Ybf) Ybf[o] = f2bf(v);
    }
  }
}

// ----------------------------------- pred_cart = segsum(f*unit) per crystal
__global__ void k_pcart(const float* __restrict__ f, const float* __restrict__ unit,
                        const int* __restrict__ dst, float* __restrict__ out) {
  __shared__ float acc[AATOMS * 3];
  int c = blockIdx.x, tid = threadIdx.x;  // 256 threads
  if (tid < AATOMS*3) acc[tid] = 0.f;
  __syncthreads();
  for (int t = tid; t < 1280; t += 256) {
    int e = c*1280 + t;
    int d = dst[e] & 63;
    float fv = f[e];
    atomicAdd(&acc[d*3+0], fv * unit[e*3+0]);
    atomicAdd(&acc[d*3+1], fv * unit[e*3+1]);
    atomicAdd(&acc[d*3+2], fv * unit[e*3+2]);
  }
  __syncthreads();
  if (tid < AATOMS*3) out[c*AATOMS*3 + tid] = acc[tid];
}

// ----------------------------------------- final fc3: (128 -> 2) per atom row
__global__ void k_fc3(const float* __restrict__ a2, const float* __restrict__ W,
                      const float* __restrict__ b, float* __restrict__ out) {
  int lane = threadIdx.x & 63;
  int wave = threadIdx.x >> 6;
  int row = blockIdx.x * 4 + wave;
  float x0 = a2[(size_t)row*HID + lane], x1 = a2[(size_t)row*HID + 64 + lane];
  float p0 = x0 * W[lane*2+0] + x1 * W[(64+lane)*2+0];
  float p1 = x0 * W[lane*2+1] + x1 * W[(64+lane)*2+1];
#pragma unroll
  for (int off = 32; off > 0; off >>= 1) {
    p0 += __shfl_down(p0, off, 64);
    p1 += __shfl_down(p1, off, 64);
  }
  if (lane == 0) {
    out[row*2+0] = p0 + b[0];
    out[row*2+1] = p1 + b[1];
  }
}

extern "C" void kernel_launch(void* const* d_in, const int* in_sizes, int n_in,
                              void* d_out, int out_size, void* d_ws, size_t ws_size,
                              hipStream_t stream) {
  const float* z        = (const float*)d_in[0];
  const float* frac     = (const float*)d_in[1];
  const float* lengths  = (const float*)d_in[2];
  const float* angles   = (const float*)d_in[3];
  const int*   atype    = (const int*)  d_in[4];
  const int*   src      = (const int*)  d_in[5];
  const int*   dst      = (const int*)  d_in[6];
  const float* emb      = (const float*)d_in[7];
  const float* W_in     = (const float*)d_in[8];
  const float* b_in     = (const float*)d_in[9];
  const float* W_edge   = (const float*)d_in[10];
  const float* b_edge   = (const float*)d_in[11];
  const float* Wb_rbf   = (const float*)d_in[12];
  const float* Wb_msg   = (const float*)d_in[13];
  const float* bb_msg   = (const float*)d_in[14];
  const float* Wb_atom  = (const float*)d_in[15];
  const float* bb_atom  = (const float*)d_in[16];
  const float* Wb_upd   = (const float*)d_in[17];
  const float* bb_upd   = (const float*)d_in[18];
  const float* W_force  = (const float*)d_in[19];
  const float* b_force  = (const float*)d_in[20];
  const float* W_fc1    = (const float*)d_in[21];
  const float* b_fc1    = (const float*)d_in[22];
  const float* W_fc2    = (const float*)d_in[23];
  const float* b_fc2    = (const float*)d_in[24];
  const float* W_fc3    = (const float*)d_in[25];
  const float* b_fc3    = (const float*)d_in[26];

  // ---- workspace layout (~190 MB) ----
  char* p = (char*)d_ws;
  float* cart = (float*)p;            p += (size_t)NATOMS*3*4;
  float* unit = (float*)p;            p += (size_t)NEDGE*3*4;
  float* dist = (float*)p;            p += (size_t)NEDGE*4;
  float* h    = (float*)p;            p += (size_t)NATOMS*HID*4;
  float* a2   = (float*)p;            p += (size_t)NATOMS*HID*4;
  float* fbuf = (float*)p;            p += (size_t)NEDGE*4;
  float* T    = (float*)p;            p += (size_t)4*DQ*128*4;
  __hip_bfloat16* h_bf = (__hip_bfloat16*)p; p += (size_t)NATOMS*HID*2;
  __hip_bfloat16* a1bf = (__hip_bfloat16*)p; p += (size_t)NATOMS*HID*2;
  __hip_bfloat16* u0t  = (__hip_bfloat16*)p; p += (size_t)NATOMS*HID*2;
  __hip_bfloat16* v0t  = (__hip_bfloat16*)p; p += (size_t)NATOMS*HID*2;
  __hip_bfloat16* uut  = (__hip_bfloat16*)p; p += (size_t)NATOMS*HID*2;
  __hip_bfloat16* vvt  = (__hip_bfloat16*)p; p += (size_t)NATOMS*HID*2;
  __hip_bfloat16* aggP = (__hip_bfloat16*)p; p += (size_t)NPART*NATOMS*HID*2;
  __hip_bfloat16* m    = (__hip_bfloat16*)p; p += (size_t)NEDGE*HID*2;
  __hip_bfloat16* WT   = (__hip_bfloat16*)p; p += (size_t)360448*2;

  __hip_bfloat16* WT_in   = WT;
  __hip_bfloat16* WTK     = WT + 49152;          // 19 K=128 blocks
  __hip_bfloat16* WT_u0   = WTK + 0*16384;
  __hip_bfloat16* WT_v0   = WTK + 1*16384;
  __hip_bfloat16* WT_updB = WTK + 2*16384;       // (uu,vv,mm) x 3
  __hip_bfloat16* WT_msg  = WTK + 11*16384;
  __hip_bfloat16* WT_atom = WTK + 14*16384;
  __hip_bfloat16* WT_fc1  = WTK + 17*16384;
  __hip_bfloat16* WT_fc2  = WTK + 18*16384;

  float* out_cart = (float*)d_out;
  float* out_at   = out_cart + NATOMS*3;

  k_wcast<<<1408, 256, 0, stream>>>(W_in, W_edge, Wb_upd, Wb_msg, Wb_atom,
                                    W_fc1, W_fc2, WT);
  k_tab<<<DQ, 128, 0, stream>>>(W_edge, Wb_rbf, T);
  k_cart<<<NATOMS/256, 256, 0, stream>>>(frac, lengths, angles, cart);
  k_edge<<<NEDGE/256, 256, 0, stream>>>(cart, src, dst, unit, dist, b_force, fbuf);
  k_hm<<<NATOMS/64, 256, 0, stream>>>(atype, z, emb, WT_in, b_in, h, h_bf);
  k_uv2<<<NATOMS/64, 256, 0, stream>>>(h_bf, WT_u0, WT_v0, u0t, v0t);
  k_minit<<<NEDGE/64, 256, 0, stream>>>(src, dst, dist, u0t, v0t, T, b_edge, m);

  for (int i = 0; i < NBLK; ++i) {
    k_msgagg<<<NCRYST*NPART, 256, 0, stream>>>(m, dist, WT_msg + i*16384,
                                               bb_msg + i*HID, T + (size_t)(1+i)*DQ*128,
                                               dst, aggP);
    k_fcm<<<NATOMS/64, 256, 0, stream>>>(nullptr, aggP, NPART, WT_atom + i*16384,
                                         bb_atom + i*HID, h, h, h_bf);
    k_uv2<<<NATOMS/64, 256, 0, stream>>>(h_bf, WT_updB + (3*i+0)*16384,
                                         WT_updB + (3*i+1)*16384, uut, vvt);
    if (i < NBLK-1) {
      k_eup<1><<<EUPGRID, 256, 0, stream>>>(src, dst, m, uut, vvt,
                                            WT_updB + (3*i+2)*16384, bb_upd + i*HID,
                                            nullptr, nullptr);
    } else {
      k_eup<2><<<EUPGRID, 256, 0, stream>>>(src, dst, m, uut, vvt,
                                            WT_updB + (3*i+2)*16384, bb_upd + i*HID,
                                            W_force, fbuf);
    }
  }
  k_pcart<<<NCRYST, 256, 0, stream>>>(fbuf, unit, dst, out_cart);
  k_fcm<<<NATOMS/64, 256, 0, stream>>>(h_bf, nullptr, 1, WT_fc1, b_fc1,
                                       nullptr, nullptr, a1bf);
  k_fcm<<<NATOMS/64, 256, 0, stream>>>(a1bf, nullptr, 1, WT_fc2, b_fc2,
                                       nullptr, a2, nullptr);
  k_fc3<<<NATOMS/4, 256, 0, stream>>>(a2, W_fc3, b_fc3, out_at);
}

// Round 21
// 851.637 us; speedup vs baseline: 1.0858x; 1.0297x over previous
//
#include <hip/hip_runtime.h>
#include <hip/hip_bf16.h>

#define NCRYST 256
#define AATOMS 64
#define KNBR   20
#define HID    128
#define LAT    256
#define NRBF   128
#define NBLK   3
#define NATOMS (NCRYST * AATOMS)   // 16384
#define NEDGE  (NATOMS * KNBR)     // 327680
#define NPART  8                   // agg partial slices per crystal
#define DQ     4096                // dist-table knots over [0, CUT]
#define PI_F   3.14159265358979323846f
#define CUT_F  6.0f
#define CHB    1040                // LDS A chunk stride: 1024 B payload + 16 B pad
#define EUPGRID 512

typedef short short8 __attribute__((ext_vector_type(8)));   // 8 bf16 (4 VGPRs)
typedef float f32x4  __attribute__((ext_vector_type(4)));   // MFMA C/D

__device__ __forceinline__ float bf2f(__hip_bfloat16 x) { return __bfloat162float(x); }
__device__ __forceinline__ __hip_bfloat16 f2bf(float x) { return __float2bfloat16(x); }
__device__ __forceinline__ float s2f(short x) {
  return __uint_as_float(((unsigned)(unsigned short)x) << 16);
}
__device__ __forceinline__ short f2s(float x) {
  union { short s; __hip_bfloat16 b; } u; u.b = f2bf(x); return u.s;
}

#define DMA16(gptr, lptr) __builtin_amdgcn_global_load_lds( \
    (const __attribute__((address_space(1))) void*)(gptr),  \
    (__attribute__((address_space(3))) void*)(lptr), 16, 0, 0)

// ---------------------------------------------------------------- cart coords
__global__ void k_cart(const float* __restrict__ frac, const float* __restrict__ lengths,
                       const float* __restrict__ angles, float* __restrict__ cart) {
  int atom = blockIdx.x * blockDim.x + threadIdx.x;
  if (atom >= NATOMS) return;
  int c = atom >> 6;
  float al = angles[c*3+0] * (PI_F/180.f);
  float be = angles[c*3+1] * (PI_F/180.f);
  float ga = angles[c*3+2] * (PI_F/180.f);
  float ca = cosf(al), cb = cosf(be), cg = cosf(ga), sg = sinf(ga);
  float a = lengths[c*3+0], b = lengths[c*3+1], cl = lengths[c*3+2];
  float cx = cl * cb;
  float cy = cl * (ca - cb*cg) / sg;
  float cz = sqrtf(fmaxf(cl*cl - cx*cx - cy*cy, 1e-8f));
  float f0 = frac[atom*3+0], f1 = frac[atom*3+1], f2 = frac[atom*3+2];
  cart[atom*3+0] = f0*a + f1*(b*cg) + f2*cx;
  cart[atom*3+1] = f1*(b*sg) + f2*cy;
  cart[atom*3+2] = f2*cz;
}

// ---------------- edge geometry: unit + dist; also init fbuf[e] = b_force
__global__ void k_edge(const float* __restrict__ cart, const int* __restrict__ src,
                       const int* __restrict__ dst, float* __restrict__ unit,
                       float* __restrict__ dist, const float* __restrict__ b_force,
                       float* __restrict__ fbuf) {
  int e = blockIdx.x * blockDim.x + threadIdx.x;
  if (e >= NEDGE) return;
  int s = src[e], d = dst[e];
  float dx = cart[d*3+0] - cart[s*3+0];
  float dy = cart[d*3+1] - cart[s*3+1];
  float dz = cart[d*3+2] - cart[s*3+2];
  float dd = sqrtf(dx*dx + dy*dy + dz*dz + 1e-12f);
  float inv = 1.f / dd;
  dist[e] = dd;
  unit[e*3+0] = dx*inv; unit[e*3+1] = dy*inv; unit[e*3+2] = dz*inv;
  fbuf[e] = b_force[0];
}

// ---------------- dist tables: T[0]=rbf@W_edge[256:384], T[1+i]=rbf@Wb_rbf[i]
__global__ __launch_bounds__(128) void k_tab(const float* __restrict__ W_edge,
                                             const float* __restrict__ Wb_rbf,
                                             float* __restrict__ T) {
  int q = blockIdx.x, n = threadIdx.x;
  __shared__ float rv[128];
  float d = (float)q * (CUT_F / (float)(DQ - 1));
  float env = 0.5f * (cosf(PI_F * fminf(d * (1.f/CUT_F), 1.f)) + 1.f);
  float t = (d - (float)n * (CUT_F/(NRBF-1))) * ((NRBF-1)/CUT_F);
  rv[n] = expf(-t*t) * env;
  __syncthreads();
  float a0 = 0.f, a1 = 0.f, a2 = 0.f, a3 = 0.f;
  for (int j = 0; j < 128; ++j) {
    float r = rv[j];
    a0 = fmaf(r, W_edge[(256 + j)*128 + n], a0);
    a1 = fmaf(r, Wb_rbf[0*16384 + j*128 + n], a1);
    a2 = fmaf(r, Wb_rbf[1*16384 + j*128 + n], a2);
    a3 = fmaf(r, Wb_rbf[2*16384 + j*128 + n], a3);
  }
  T[(0*DQ + q)*128 + n] = a0;
  T[(1*DQ + q)*128 + n] = a1;
  T[(2*DQ + q)*128 + n] = a2;
  T[(3*DQ + q)*128 + n] = a3;
}

// ----------------- weights -> bf16 n-major K=128 blocks (W_in stays K=384)
__global__ void k_wcast(const float* __restrict__ W_in, const float* __restrict__ W_edge,
                        const float* __restrict__ Wb_upd, const float* __restrict__ Wb_msg,
                        const float* __restrict__ Wb_atom, const float* __restrict__ W_fc1,
                        const float* __restrict__ W_fc2, __hip_bfloat16* __restrict__ WT) {
  int idx = blockIdx.x * 256 + threadIdx.x;
  if (idx >= 360448) return;
  if (idx < 49152) {
    int n = idx / 384, k = idx % 384;
    WT[idx] = f2bf(W_in[k*128 + n]);
    return;
  }
  int t = idx - 49152;
  int b = t >> 14, q = t & 16383;
  int n = q >> 7, k = q & 127;
  const float* S; int krow;
  if (b == 0)       { S = W_edge; krow = k; }
  else if (b == 1)  { S = W_edge; krow = 128 + k; }
  else if (b <= 10) { int i = (b-2)/3, part = (b-2)%3;
                      S = Wb_upd + i*49152; krow = part*128 + k; }
  else if (b <= 13) { S = Wb_msg + (b-11)*16384; krow = k; }
  else if (b <= 16) { S = Wb_atom + (b-14)*16384; krow = k; }
  else if (b == 17) { S = W_fc1; krow = k; }
  else              { S = W_fc2; krow = k; }
  WT[idx] = f2bf(S[krow*128 + n]);
}

// ============ MFMA h: h = relu([emb[atype]|z]@W_in + b), 64 rows/block
__global__ __launch_bounds__(256) void k_hm(
    const int* __restrict__ atype, const float* __restrict__ z,
    const float* __restrict__ emb, const __hip_bfloat16* __restrict__ WTin,
    const float* __restrict__ b, float* __restrict__ h,
    __hip_bfloat16* __restrict__ h_bf) {
  const int tid = threadIdx.x;
  const int w = tid >> 6, lane = tid & 63, ln = lane & 15, qd = lane >> 4;
  const int row0w = blockIdx.x * 64 + w * 16;
  const int arow = row0w + ln;
  const float* esrc = emb + (size_t)atype[arow] * 128;
  const float* zsrc = z + (size_t)(arow >> 6) * LAT;

  short8 af[12];
#pragma unroll
  for (int ks = 0; ks < 4; ++ks) {
    float4 v0 = *(const float4*)(esrc + ks*32 + qd*8);
    float4 v1 = *(const float4*)(esrc + ks*32 + qd*8 + 4);
    af[ks] = (short8){f2s(v0.x),f2s(v0.y),f2s(v0.z),f2s(v0.w),
                      f2s(v1.x),f2s(v1.y),f2s(v1.z),f2s(v1.w)};
  }
#pragma unroll
  for (int ks = 4; ks < 12; ++ks) {
    float4 v0 = *(const float4*)(zsrc + (ks-4)*32 + qd*8);
    float4 v1 = *(const float4*)(zsrc + (ks-4)*32 + qd*8 + 4);
    af[ks] = (short8){f2s(v0.x),f2s(v0.y),f2s(v0.z),f2s(v0.w),
                      f2s(v1.x),f2s(v1.y),f2s(v1.z),f2s(v1.w)};
  }

  const short* Wb = (const short*)WTin + ln*384 + qd*8;
  f32x4 acc[8];
#pragma unroll
  for (int ct = 0; ct < 8; ++ct) acc[ct] = (f32x4){0,0,0,0};
#pragma unroll
  for (int ks = 0; ks < 12; ++ks)
#pragma unroll
    for (int ct = 0; ct < 8; ++ct)
      acc[ct] = __builtin_amdgcn_mfma_f32_16x16x32_bf16(af[ks],
                  *(const short8*)(Wb + ct*16*384 + ks*32), acc[ct], 0,0,0);

#pragma unroll
  for (int ct = 0; ct < 8; ++ct) {
    int col = ct*16 + ln;
    float bias = b[col];
#pragma unroll
    for (int reg = 0; reg < 4; ++reg) {
      int crow = row0w + qd*4 + reg;
      float v = fmaxf(acc[ct][reg] + bias, 0.f);
      size_t o = (size_t)crow*128 + col;
      h[o] = v;
      h_bf[o] = f2bf(v);
    }
  }
}

// ============ dual projection: O1 = A@WT1, O2 = A@WT2 (no bias/relu, bf16)
__global__ __launch_bounds__(256) void k_uv2(
    const __hip_bfloat16* __restrict__ A,
    const __hip_bfloat16* __restrict__ WT1, const __hip_bfloat16* __restrict__ WT2,
    __hip_bfloat16* __restrict__ O1, __hip_bfloat16* __restrict__ O2) {
  const int tid = threadIdx.x;
  const int w = tid >> 6, lane = tid & 63, ln = lane & 15, qd = lane >> 4;
  const int row0w = blockIdx.x * 64 + w * 16;
  const int arow = row0w + ln;

  short8 af[4];
  const short* pa = (const short*)A + (size_t)arow*128 + qd*8;
#pragma unroll
  for (int ks = 0; ks < 4; ++ks) af[ks] = *(const short8*)(pa + ks*32);

  f32x4 a1[8], a2[8];
#pragma unroll
  for (int ct = 0; ct < 8; ++ct) { a1[ct] = (f32x4){0,0,0,0}; a2[ct] = (f32x4){0,0,0,0}; }
#pragma unroll
  for (int ct = 0; ct < 8; ++ct) {
    const short* b1 = (const short*)WT1 + (ct*16 + ln)*128 + qd*8;
    const short* b2 = (const short*)WT2 + (ct*16 + ln)*128 + qd*8;
#pragma unroll
    for (int ks = 0; ks < 4; ++ks) {
      a1[ct] = __builtin_amdgcn_mfma_f32_16x16x32_bf16(af[ks], *(const short8*)(b1 + ks*32), a1[ct], 0,0,0);
      a2[ct] = __builtin_amdgcn_mfma_f32_16x16x32_bf16(af[ks], *(const short8*)(b2 + ks*32), a2[ct], 0,0,0);
    }
  }
#pragma unroll
  for (int ct = 0; ct < 8; ++ct) {
    int col = ct*16 + ln;
#pragma unroll
    for (int reg = 0; reg < 4; ++reg) {
      size_t o = (size_t)(row0w + qd*4 + reg)*128 + col;
      O1[o] = f2bf(a1[ct][reg]);
      O2[o] = f2bf(a2[ct][reg]);
    }
  }
}

// ============ m init v2: m = relu(u0[src] + v0[dst] + T0(d) + b)
__global__ __launch_bounds__(256) void k_minit(
    const int* __restrict__ src, const int* __restrict__ dst,
    const float* __restrict__ dist,
    const __hip_bfloat16* __restrict__ u0, const __hip_bfloat16* __restrict__ v0,
    const float* __restrict__ T0, const float* __restrict__ b,
    __hip_bfloat16* __restrict__ m) {
  const int t = threadIdx.x;
  const int li = t & 15, ei = t >> 4;
  float bcol[8];
#pragma unroll
  for (int u = 0; u < 8; ++u) bcol[u] = b[li*8 + u];

  int e[4]; float dd[4]; short8 us[4], vs[4];
#pragma unroll
  for (int g = 0; g < 4; ++g) {
    e[g] = blockIdx.x*64 + g*16 + ei;
    dd[g] = dist[e[g]];
    int s = src[e[g]], d = dst[e[g]];
    us[g] = *(const short8*)((const short*)u0 + (size_t)s*128 + li*8);
    vs[g] = *(const short8*)((const short*)v0 + (size_t)d*128 + li*8);
  }
  float t0v[4][8], t1v[4][8]; float fr[4]; bool in[4];
#pragma unroll
  for (int g = 0; g < 4; ++g) {
    in[g] = dd[g] < CUT_F;
    float x = fminf(dd[g], CUT_F) * ((float)(DQ - 1) / CUT_F);
    int i0 = (int)x;
    fr[g] = x - (float)i0;
    const float* tp = T0 + (size_t)i0*128 + li*8;
    *(float4*)&t0v[g][0] = *(const float4*)tp;
    *(float4*)&t0v[g][4] = *(const float4*)(tp + 4);
    *(float4*)&t1v[g][0] = *(const float4*)(tp + 128);
    *(float4*)&t1v[g][4] = *(const float4*)(tp + 132);
  }
#pragma unroll
  for (int g = 0; g < 4; ++g) {
    short8 o;
#pragma unroll
    for (int u = 0; u < 8; ++u) {
      float tv = in[g] ? fmaf(fr[g], t1v[g][u] - t0v[g][u], t0v[g][u]) : 0.f;
      float v = s2f(us[g][u]) + s2f(vs[g][u]) + tv + bcol[u];
      o[u] = f2s(fmaxf(v, 0.f));
    }
    *(uint4*)((short*)m + (size_t)e[g]*128 + li*8) = *(uint4*)&o;
  }
}

// ============ m update (K=128, B in LDS, persistent blocks, DMA dbuf)
template<int MODE>
__global__ __launch_bounds__(256) void k_eup(
    const int* __restrict__ src, const int* __restrict__ dst,
    __hip_bfloat16* __restrict__ m,
    const __hip_bfloat16* __restrict__ uu, const __hip_bfloat16* __restrict__ vv,
    const __hip_bfloat16* __restrict__ WTmm, const float* __restrict__ b,
    const float* __restrict__ Wf, float* __restrict__ fout) {
  __shared__ short Bs[128 * 132];                     // 33.8 KB
  __shared__ __align__(16) char Abuf[2][17 * CHB];    // 2 x 17.7 KB
  const int tid = threadIdx.x;
  const int w = tid >> 6, lane = tid & 63, ln = lane & 15, qd = lane >> 4;
  const int cg = w & 1, rh = w >> 1;
  const int NT = NEDGE / 64;

#pragma unroll
  for (int i = 0; i < 8; ++i) {
    int g = i * 256 + tid;
    int colb = g >> 4, ch = g & 15;
    *(uint4*)&Bs[colb*132 + ch*8] = ((const uint4*)((const short*)WTmm + colb*128))[ch];
  }

  float bias4[4], wf4[4];
#pragma unroll
  for (int ct = 0; ct < 4; ++ct) bias4[ct] = b[cg*64 + ct*16 + ln];
  if constexpr (MODE == 2) {
#pragma unroll
    for (int ct = 0; ct < 4; ++ct) wf4[ct] = Wf[cg*64 + ct*16 + ln];
  }

  {
    int tile = blockIdx.x;
#pragma unroll
    for (int t4 = 0; t4 < 4; ++t4) {
      int chunk = w * 4 + t4;
      const short* gp = (const short*)m + (size_t)(tile*64 + chunk*4)*128 + lane*8;
      DMA16(gp, Abuf[0] + chunk * CHB);
    }
  }

  int it = 0;
  for (int tile = blockIdx.x; tile < NT; tile += EUPGRID, ++it) {
    const int nb = it & 1;
    int ntile = tile + EUPGRID;
    if (ntile < NT) {
#pragma unroll
      for (int t4 = 0; t4 < 4; ++t4) {
        int chunk = w * 4 + t4;
        const short* gp = (const short*)m + (size_t)(ntile*64 + chunk*4)*128 + lane*8;
        DMA16(gp, Abuf[nb^1] + chunk * CHB);
      }
      __builtin_amdgcn_s_waitcnt(0x0F74);   // drain all but next tile's 4 DMAs
    } else {
      __builtin_amdgcn_s_waitcnt(0x0F70);   // drain everything
    }
    __syncthreads();

    const char* Ab = Abuf[nb];
    int e0 = tile * 64;

    f32x4 acc0[4], acc1[4];
#pragma unroll
    for (int ct = 0; ct < 4; ++ct) { acc0[ct] = (f32x4){0,0,0,0}; acc1[ct] = (f32x4){0,0,0,0}; }
    const int rowA = rh*32 + ln, rowB = rowA + 16;
#pragma unroll
    for (int ks = 0; ks < 4; ++ks) {
      short8 aA = *(const short8*)(Ab + (rowA>>2)*CHB + (rowA&3)*256 + ks*64 + qd*16);
      short8 aB = *(const short8*)(Ab + (rowB>>2)*CHB + (rowB&3)*256 + ks*64 + qd*16);
#pragma unroll
      for (int ct = 0; ct < 4; ++ct) {
        short8 bb = *(const short8*)&Bs[(cg*64 + ct*16 + ln)*132 + ks*32 + qd*8];
        acc0[ct] = __builtin_amdgcn_mfma_f32_16x16x32_bf16(aA, bb, acc0[ct], 0,0,0);
        acc1[ct] = __builtin_amdgcn_mfma_f32_16x16x32_bf16(aB, bb, acc1[ct], 0,0,0);
      }
    }

    float vreg[2][4][4];
#pragma unroll
    for (int mt = 0; mt < 2; ++mt) {
      const f32x4* acc = mt ? acc1 : acc0;
#pragma unroll
      for (int reg = 0; reg < 4; ++reg) {
        int lrow = rh*32 + mt*16 + qd*4 + reg;
        int e = e0 + lrow;
        int srow = src[e], drow = dst[e];
        float fp = 0.f;
#pragma unroll
        for (int ct = 0; ct < 4; ++ct) {
          int col = cg*64 + ct*16 + ln;
          float um = s2f(*((const short*)uu + (size_t)srow*128 + col));
          float vm = s2f(*((const short*)vv + (size_t)drow*128 + col));
          float res = s2f(*(const short*)(Ab + (lrow>>2)*CHB + (lrow&3)*256 + col*2));
          float val = fmaxf(acc[ct][reg] + bias4[ct] + um + vm, 0.f) + res;
          if constexpr (MODE == 1) vreg[mt][reg][ct] = val;
          else fp = fmaf(val, wf4[ct], fp);
        }
        if constexpr (MODE == 2) {
          fp += __shfl_xor(fp, 1, 64);
          fp += __shfl_xor(fp, 2, 64);
          fp += __shfl_xor(fp, 4, 64);
          fp += __shfl_xor(fp, 8, 64);
          if (ln == 0) atomicAdd(&fout[e], fp);
        }
      }
    }

    if constexpr (MODE == 1) {
      __syncthreads();
      short* res = (short*)Abuf[nb];
#pragma unroll
      for (int mt = 0; mt < 2; ++mt)
#pragma unroll
        for (int reg = 0; reg < 4; ++reg) {
          int lrow = rh*32 + mt*16 + qd*4 + reg;
#pragma unroll
          for (int ct = 0; ct < 4; ++ct)
            res[lrow*136 + cg*64 + ct*16 + ln] = f2s(vreg[mt][reg][ct]);
        }
      __syncthreads();
#pragma unroll
      for (int i = 0; i < 4; ++i) {
        int g = i * 256 + tid;
        int row = g >> 4, ch = g & 15;
        *(uint4*)((short*)m + (size_t)(e0 + row)*128 + ch*8) =
            *(const uint4*)((const char*)Abuf[nb] + row*272 + ch*16);
      }
      __syncthreads();
    } else {
      __syncthreads();
    }
  }
}

// ===== fused msg+segsum v6: pipelined m DMA + gate-table register prefetch.
__global__ __launch_bounds__(256) void k_msgagg(
    const __hip_bfloat16* __restrict__ m, const float* __restrict__ dist,
    const __hip_bfloat16* __restrict__ WmT, const float* __restrict__ bm,
    const float* __restrict__ Tg, const int* __restrict__ dst,
    __hip_bfloat16* __restrict__ aggP) {
  __shared__ float agg[64 * 132];                    // 33.8 KB
  __shared__ float gate[16 * 132];                   //  8.4 KB
  __shared__ __align__(16) char Mb[2][4 * CHB];      //  8.3 KB (16 rows/tile)
  const int tid = threadIdx.x;
  const int c = blockIdx.x & 255, pq = blockIdx.x >> 8;
  const int w = tid >> 6, lane = tid & 63, ln = lane & 15, qd = lane >> 4;
  const int ei = tid >> 4, li = tid & 15;   // phase-A role

  for (int i = tid; i < 64*132; i += 256) agg[i] = 0.f;
  float bias2[2];
#pragma unroll
  for (int ct = 0; ct < 2; ++ct) bias2[ct] = bm[(w*2+ct)*16 + ln];

  const int ebase = c * 1280 + pq * 160;

  {
    const short* gp = (const short*)m + (size_t)(ebase + w*4)*128 + lane*8;
    DMA16(gp, Mb[0] + w * CHB);
  }
  float4 ta0, ta1, tb0, tb1; float frc, mskc;
  {
    float d0 = dist[ebase + ei];
    mskc = (d0 < CUT_F) ? 1.f : 0.f;
    float x = fminf(d0, CUT_F) * ((float)(DQ - 1) / CUT_F);
    int i0 = (int)x;
    frc = x - (float)i0;
    const float* tp = Tg + (size_t)i0*128 + li*8;
    ta0 = *(const float4*)tp;
    ta1 = *(const float4*)(tp + 4);
    tb0 = *(const float4*)(tp + 128);
    tb1 = *(const float4*)(tp + 132);
  }
  float dnxt = dist[ebase + 16 + ei];
  __syncthreads();

  for (int s = 0; s < 10; ++s) {
    int e0 = ebase + s * 16;

    {
      float g8[8];
      g8[0] = mskc * fmaf(frc, tb0.x-ta0.x, ta0.x);
      g8[1] = mskc * fmaf(frc, tb0.y-ta0.y, ta0.y);
      g8[2] = mskc * fmaf(frc, tb0.z-ta0.z, ta0.z);
      g8[3] = mskc * fmaf(frc, tb0.w-ta0.w, ta0.w);
      g8[4] = mskc * fmaf(frc, tb1.x-ta1.x, ta1.x);
      g8[5] = mskc * fmaf(frc, tb1.y-ta1.y, ta1.y);
      g8[6] = mskc * fmaf(frc, tb1.z-ta1.z, ta1.z);
      g8[7] = mskc * fmaf(frc, tb1.w-ta1.w, ta1.w);
      *(float4*)&gate[ei*132 + li*8]     = *(float4*)&g8[0];
      *(float4*)&gate[ei*132 + li*8 + 4] = *(float4*)&g8[4];
    }

    if (s < 9) {
      mskc = (dnxt < CUT_F) ? 1.f : 0.f;
      float x = fminf(dnxt, CUT_F) * ((float)(DQ - 1) / CUT_F);
      int i0 = (int)x;
      frc = x - (float)i0;
      const float* tp = Tg + (size_t)i0*128 + li*8;
      ta0 = *(const float4*)tp;
      ta1 = *(const float4*)(tp + 4);
      tb0 = *(const float4*)(tp + 128);
      tb1 = *(const float4*)(tp + 132);
      const short* gp = (const short*)m + (size_t)(e0 + 16 + w*4)*128 + lane*8;
      DMA16(gp, Mb[(s+1) & 1] + w * CHB);
      int dn_idx = (s < 8) ? (e0 + 32 + ei) : (e0 + 16 + ei);
      dnxt = dist[dn_idx];
      __builtin_amdgcn_s_waitcnt(0x0F76);
    } else {
      __builtin_amdgcn_s_waitcnt(0x0F70);
    }
    __syncthreads();

    const char* Ms = Mb[s & 1];
    short8 am[4];
#pragma unroll
    for (int ks = 0; ks < 4; ++ks)
      am[ks] = *(const short8*)(Ms + (ln>>2)*CHB + (ln&3)*256 + ks*64 + qd*16);
    int d4[4];
#pragma unroll
    for (int reg = 0; reg < 4; ++reg) d4[reg] = dst[e0 + qd*4 + reg] & 63;

    f32x4 accM[2];
#pragma unroll
    for (int ct = 0; ct < 2; ++ct) accM[ct] = (f32x4){0,0,0,0};
#pragma unroll
    for (int ct = 0; ct < 2; ++ct) {
      const short* bmp = (const short*)WmT + ((w*2+ct)*16 + ln)*128 + qd*8;
#pragma unroll
      for (int ks = 0; ks < 4; ++ks)
        accM[ct] = __builtin_amdgcn_mfma_f32_16x16x32_bf16(am[ks],
                     *(const short8*)(bmp + ks*32), accM[ct], 0,0,0);
    }
#pragma unroll
    for (int ct = 0; ct < 2; ++ct) {
      int col = (w*2+ct)*16 + ln;
#pragma unroll
      for (int reg = 0; reg < 4; ++reg) {
        float g = gate[(qd*4 + reg)*132 + col];
        float v = fmaxf(accM[ct][reg] + bias2[ct], 0.f) * g;
        if (v != 0.f) atomicAdd(&agg[d4[reg]*132 + col], v);
      }
    }
    __syncthreads();
  }

  __hip_bfloat16* outp = aggP + ((size_t)pq * NATOMS + c * 64) * HID;
  for (int i = tid; i < 64*128; i += 256) {
    int a = i >> 7, col = i & 127;
    outp[a*HID + col] = f2bf(agg[a*132 + col]);
  }
}

// ============ FUSED fc+uv: h += relu(sum(slices)@Wa + ba); then
// u = h@Wu, v = h@Wv via LDS C->A layout round-trip. 64 rows/block.
__global__ __launch_bounds__(256) void k_fcuv(
    const __hip_bfloat16* __restrict__ slices,
    const __hip_bfloat16* __restrict__ WTa, const float* __restrict__ ba,
    float* __restrict__ h, __hip_bfloat16* __restrict__ h_bf,
    const __hip_bfloat16* __restrict__ WTu, const __hip_bfloat16* __restrict__ WTv,
    __hip_bfloat16* __restrict__ uo, __hip_bfloat16* __restrict__ vo) {
  __shared__ short ht[64 * 136];   // 17.4 KB fresh-h tile (row pitch 136)
  const int tid = threadIdx.x;
  const int w = tid >> 6, lane = tid & 63, ln = lane & 15, qd = lane >> 4;
  const int row0w = blockIdx.x * 64 + w * 16;
  const int arow = row0w + ln;

  // ---- phase 1: h update (slice sum -> MFMA -> residual) ----
  short8 af[4];
#pragma unroll
  for (int ks = 0; ks < 4; ++ks) {
    float s[8] = {0,0,0,0,0,0,0,0};
#pragma unroll
    for (int p = 0; p < NPART; ++p) {
      short8 v = *(const short8*)((const short*)slices +
                   (size_t)p*NATOMS*128 + (size_t)arow*128 + qd*8 + ks*32);
#pragma unroll
      for (int u = 0; u < 8; ++u) s[u] += s2f(v[u]);
    }
    af[ks] = (short8){f2s(s[0]),f2s(s[1]),f2s(s[2]),f2s(s[3]),
                      f2s(s[4]),f2s(s[5]),f2s(s[6]),f2s(s[7])};
  }

  const short* Wb = (const short*)WTa + ln*128 + qd*8;
  f32x4 acc[8];
#pragma unroll
  for (int ct = 0; ct < 8; ++ct) acc[ct] = (f32x4){0,0,0,0};
#pragma unroll
  for (int ct = 0; ct < 8; ++ct)
#pragma unroll
    for (int ks = 0; ks < 4; ++ks)
      acc[ct] = __builtin_amdgcn_mfma_f32_16x16x32_bf16(af[ks],
                  *(const short8*)(Wb + ct*16*128 + ks*32), acc[ct], 0,0,0);

#pragma unroll
  for (int ct = 0; ct < 8; ++ct) {
    int col = ct*16 + ln;
    float bias = ba[col];
#pragma unroll
    for (int reg = 0; reg < 4; ++reg) {
      int lrow = w*16 + qd*4 + reg;          // row within block's 64
      size_t o = (size_t)(blockIdx.x*64 + lrow)*128 + col;
      float v = fmaxf(acc[ct][reg] + bias, 0.f) + h[o];
      h[o] = v;
      short hb = f2s(v);
      h_bf[o] = *(__hip_bfloat16*)&hb;
      ht[lrow*136 + col] = hb;
    }
  }
  __syncthreads();

  // ---- phase 2: dual projection from LDS tile ----
  short8 ah[4];
  const short* ph = &ht[(w*16 + ln)*136 + qd*8];
#pragma unroll
  for (int ks = 0; ks < 4; ++ks) ah[ks] = *(const short8*)(ph + ks*32);

  f32x4 a1[8], a2[8];
#pragma unroll
  for (int ct = 0; ct < 8; ++ct) { a1[ct] = (f32x4){0,0,0,0}; a2[ct] = (f32x4){0,0,0,0}; }
#pragma unroll
  for (int ct = 0; ct < 8; ++ct) {
    const short* b1 = (const short*)WTu + (ct*16 + ln)*128 + qd*8;
    const short* b2 = (const short*)WTv + (ct*16 + ln)*128 + qd*8;
#pragma unroll
    for (int ks = 0; ks < 4; ++ks) {
      a1[ct] = __builtin_amdgcn_mfma_f32_16x16x32_bf16(ah[ks], *(const short8*)(b1 + ks*32), a1[ct], 0,0,0);
      a2[ct] = __builtin_amdgcn_mfma_f32_16x16x32_bf16(ah[ks], *(const short8*)(b2 + ks*32), a2[ct], 0,0,0);
    }
  }
#pragma unroll
  for (int ct = 0; ct < 8; ++ct) {
    int col = ct*16 + ln;
#pragma unroll
    for (int reg = 0; reg < 4; ++reg) {
      size_t o = (size_t)(row0w + qd*4 + reg)*128 + col;
      uo[o] = f2bf(a1[ct][reg]);
      vo[o] = f2bf(a2[ct][reg]);
    }
  }
}

// ============ FUSED head: a1 = relu(h@W1+b1); a2 = relu(a1@W2+b2);
// out = a2@W3 + b3  (fc3 reduced in-wave). 64 rows/block.
__global__ __launch_bounds__(256) void k_head(
    const __hip_bfloat16* __restrict__ h_bf,
    const __hip_bfloat16* __restrict__ WT1, const float* __restrict__ b1,
    const __hip_bfloat16* __restrict__ WT2, const float* __restrict__ b2,
    const float* __restrict__ W3, const float* __restrict__ b3,
    float* __restrict__ out) {
  __shared__ short t1[64 * 136];   // 17.4 KB a1 tile
  const int tid = threadIdx.x;
  const int w = tid >> 6, lane = tid & 63, ln = lane & 15, qd = lane >> 4;
  const int row0w = blockIdx.x * 64 + w * 16;
  const int arow = row0w + ln;

  // ---- fc1 ----
  short8 af[4];
  const short* pa = (const short*)h_bf + (size_t)arow*128 + qd*8;
#pragma unroll
  for (int ks = 0; ks < 4; ++ks) af[ks] = *(const short8*)(pa + ks*32);

  f32x4 acc[8];
#pragma unroll
  for (int ct = 0; ct < 8; ++ct) acc[ct] = (f32x4){0,0,0,0};
#pragma unroll
  for (int ct = 0; ct < 8; ++ct) {
    const short* bb = (const short*)WT1 + (ct*16 + ln)*128 + qd*8;
#pragma unroll
    for (int ks = 0; ks < 4; ++ks)
      acc[ct] = __builtin_amdgcn_mfma_f32_16x16x32_bf16(af[ks],
                  *(const short8*)(bb + ks*32), acc[ct], 0,0,0);
  }
#pragma unroll
  for (int ct = 0; ct < 8; ++ct) {
    int col = ct*16 + ln;
    float bias = b1[col];
#pragma unroll
    for (int reg = 0; reg < 4; ++reg) {
      int lrow = w*16 + qd*4 + reg;
      t1[lrow*136 + col] = f2s(fmaxf(acc[ct][reg] + bias, 0.f));
    }
  }
  __syncthreads();

  // ---- fc2 ----
  short8 a1f[4];
  const short* p1 = &t1[(w*16 + ln)*136 + qd*8];
#pragma unroll
  for (int ks = 0; ks < 4; ++ks) a1f[ks] = *(const short8*)(p1 + ks*32);

  f32x4 acc2[8];
#pragma unroll
  for (int ct = 0; ct < 8; ++ct) acc2[ct] = (f32x4){0,0,0,0};
#pragma unroll
  for (int ct = 0; ct < 8; ++ct) {
    const short* bb = (const short*)WT2 + (ct*16 + ln)*128 + qd*8;
#pragma unroll
    for (int ks = 0; ks < 4; ++ks)
      acc2[ct] = __builtin_amdgcn_mfma_f32_16x16x32_bf16(a1f[ks],
                   *(const short8*)(bb + ks*32), acc2[ct], 0,0,0);
  }

  // ---- fc3 (in-register): per (reg): p_j = sum_ct a2 * W3[col][j] ----
  float w3a[8], w3b[8];
#pragma unroll
  for (int ct = 0; ct < 8; ++ct) {
    int col = ct*16 + ln;
    w3a[ct] = W3[col*2+0];
    w3b[ct] = W3[col*2+1];
  }
#pragma unroll
  for (int reg = 0; reg < 4; ++reg) {
    float p0 = 0.f, p1v = 0.f;
#pragma unroll
    for (int ct = 0; ct < 8; ++ct) {
      float a2v = fmaxf(acc2[ct][reg] + b2[ct*16 + ln], 0.f);
      p0  = fmaf(a2v, w3a[ct], p0);
      p1v = fmaf(a2v, w3b[ct], p1v);
    }
    p0  += __shfl_xor(p0, 1, 64);  p1v += __shfl_xor(p1v, 1, 64);
    p0  += __shfl_xor(p0, 2, 64);  p1v += __shfl_xor(p1v, 2, 64);
    p0  += __shfl_xor(p0, 4, 64);  p1v += __shfl_xor(p1v, 4, 64);
    p0  += __shfl_xor(p0, 8, 64);  p1v += __shfl_xor(p1v, 8, 64);
    if (ln == 0) {
      int row = row0w + qd*4 + reg;
      out[row*2+0] = p0 + b3[0];
      out[row*2+1] = p1v + b3[1];
    }
  }
}

// ----------------------------------- pred_cart = segsum(f*unit) per crystal
__global__ void k_pcart(const float* __restrict__ f, const float* __restrict__ unit,
                        const int* __restrict__ dst, float* __restrict__ out) {
  __shared__ float acc[AATOMS * 3];
  int c = blockIdx.x, tid = threadIdx.x;  // 256 threads
  if (tid < AATOMS*3) acc[tid] = 0.f;
  __syncthreads();
  for (int t = tid; t < 1280; t += 256) {
    int e = c*1280 + t;
    int d = dst[e] & 63;
    float fv = f[e];
    atomicAdd(&acc[d*3+0], fv * unit[e*3+0]);
    atomicAdd(&acc[d*3+1], fv * unit[e*3+1]);
    atomicAdd(&acc[d*3+2], fv * unit[e*3+2]);
  }
  __syncthreads();
  if (tid < AATOMS*3) out[c*AATOMS*3 + tid] = acc[tid];
}

extern "C" void kernel_launch(void* const* d_in, const int* in_sizes, int n_in,
                              void* d_out, int out_size, void* d_ws, size_t ws_size,
                              hipStream_t stream) {
  const float* z        = (const float*)d_in[0];
  const float* frac     = (const float*)d_in[1];
  const float* lengths  = (const float*)d_in[2];
  const float* angles   = (const float*)d_in[3];
  const int*   atype    = (const int*)  d_in[4];
  const int*   src      = (const int*)  d_in[5];
  const int*   dst      = (const int*)  d_in[6];
  const float* emb      = (const float*)d_in[7];
  const float* W_in     = (const float*)d_in[8];
  const float* b_in     = (const float*)d_in[9];
  const float* W_edge   = (const float*)d_in[10];
  const float* b_edge   = (const float*)d_in[11];
  const float* Wb_rbf   = (const float*)d_in[12];
  const float* Wb_msg   = (const float*)d_in[13];
  const float* bb_msg   = (const float*)d_in[14];
  const float* Wb_atom  = (const float*)d_in[15];
  const float* bb_atom  = (const float*)d_in[16];
  const float* Wb_upd   = (const float*)d_in[17];
  const float* bb_upd   = (const float*)d_in[18];
  const float* W_force  = (const float*)d_in[19];
  const float* b_force  = (const float*)d_in[20];
  const float* W_fc1    = (const float*)d_in[21];
  const float* b_fc1    = (const float*)d_in[22];
  const float* W_fc2    = (const float*)d_in[23];
  const float* b_fc2    = (const float*)d_in[24];
  const float* W_fc3    = (const float*)d_in[25];
  const float* b_fc3    = (const float*)d_in[26];

  // ---- workspace layout (~190 MB) ----
  char* p = (char*)d_ws;
  float* cart = (float*)p;            p += (size_t)NATOMS*3*4;
  float* unit = (float*)p;            p += (size_t)NEDGE*3*4;
  float* dist = (float*)p;            p += (size_t)NEDGE*4;
  float* h    = (float*)p;            p += (size_t)NATOMS*HID*4;
  float* fbuf = (float*)p;            p += (size_t)NEDGE*4;
  float* T    = (float*)p;            p += (size_t)4*DQ*128*4;
  __hip_bfloat16* h_bf = (__hip_bfloat16*)p; p += (size_t)NATOMS*HID*2;
  __hip_bfloat16* u0t  = (__hip_bfloat16*)p; p += (size_t)NATOMS*HID*2;
  __hip_bfloat16* v0t  = (__hip_bfloat16*)p; p += (size_t)NATOMS*HID*2;
  __hip_bfloat16* uut  = (__hip_bfloat16*)p; p += (size_t)NATOMS*HID*2;
  __hip_bfloat16* vvt  = (__hip_bfloat16*)p; p += (size_t)NATOMS*HID*2;
  __hip_bfloat16* aggP = (__hip_bfloat16*)p; p += (size_t)NPART*NATOMS*HID*2;
  __hip_bfloat16* m    = (__hip_bfloat16*)p; p += (size_t)NEDGE*HID*2;
  __hip_bfloat16* WT   = (__hip_bfloat16*)p; p += (size_t)360448*2;

  __hip_bfloat16* WT_in   = WT;
  __hip_bfloat16* WTK     = WT + 49152;          // 19 K=128 blocks
  __hip_bfloat16* WT_u0   = WTK + 0*16384;
  __hip_bfloat16* WT_v0   = WTK + 1*16384;
  __hip_bfloat16* WT_updB = WTK + 2*16384;       // (uu,vv,mm) x 3
  __hip_bfloat16* WT_msg  = WTK + 11*16384;
  __hip_bfloat16* WT_atom = WTK + 14*16384;
  __hip_bfloat16* WT_fc1  = WTK + 17*16384;
  __hip_bfloat16* WT_fc2  = WTK + 18*16384;

  float* out_cart = (float*)d_out;
  float* out_at   = out_cart + NATOMS*3;

  k_wcast<<<1408, 256, 0, stream>>>(W_in, W_edge, Wb_upd, Wb_msg, Wb_atom,
                                    W_fc1, W_fc2, WT);
  k_tab<<<DQ, 128, 0, stream>>>(W_edge, Wb_rbf, T);
  k_cart<<<NATOMS/256, 256, 0, stream>>>(frac, lengths, angles, cart);
  k_edge<<<NEDGE/256, 256, 0, stream>>>(cart, src, dst, unit, dist, b_force, fbuf);
  k_hm<<<NATOMS/64, 256, 0, stream>>>(atype, z, emb, WT_in, b_in, h, h_bf);
  k_uv2<<<NATOMS/64, 256, 0, stream>>>(h_bf, WT_u0, WT_v0, u0t, v0t);
  k_minit<<<NEDGE/64, 256, 0, stream>>>(src, dst, dist, u0t, v0t, T, b_edge, m);

  for (int i = 0; i < NBLK; ++i) {
    k_msgagg<<<NCRYST*NPART, 256, 0, stream>>>(m, dist, WT_msg + i*16384,
                                               bb_msg + i*HID, T + (size_t)(1+i)*DQ*128,
                                               dst, aggP);
    k_fcuv<<<NATOMS/64, 256, 0, stream>>>(aggP, WT_atom + i*16384, bb_atom + i*HID,
                                          h, h_bf,
                                          WT_updB + (3*i+0)*16384,
                                          WT_updB + (3*i+1)*16384, uut, vvt);
    if (i < NBLK-1) {
      k_eup<1><<<EUPGRID, 256, 0, stream>>>(src, dst, m, uut, vvt,
                                            WT_updB + (3*i+2)*16384, bb_upd + i*HID,
                                            nullptr, nullptr);
    } else {
      k_eup<2><<<EUPGRID, 256, 0, stream>>>(src, dst, m, uut, vvt,
                                            WT_updB + (3*i+2)*16384, bb_upd + i*HID,
                                            W_force, fbuf);
    }
  }
  k_pcart<<<NCRYST, 256, 0, stream>>>(fbuf, unit, dst, out_cart);
  k_head<<<NATOMS/64, 256, 0, stream>>>(h_bf, WT_fc1, b_fc1, WT_fc2, b_fc2,
                                        W_fc3, b_fc3, out_at);
}